// Round 1
// baseline (529.103 us; speedup 1.0000x reference)
//
#include <hip/hip_runtime.h>

typedef unsigned short u16;
typedef __attribute__((ext_vector_type(8))) short short8_t;
typedef __attribute__((ext_vector_type(4))) float floatx4;

typedef const void __attribute__((address_space(1)))* gas_ptr;
typedef void __attribute__((address_space(3)))* las_ptr;

__device__ __forceinline__ float bf2f(u16 u){
  union { unsigned i; float f; } v; v.i = ((unsigned)u) << 16; return v.f;
}
__device__ __forceinline__ u16 f2bf(float x){
  unsigned u = __float_as_uint(x);
  return (u16)((u + 0x7FFFu + ((u >> 16) & 1u)) >> 16);
}

// ---------------- small prep kernels ----------------

__global__ __launch_bounds__(256) void k_conv(const float* __restrict__ x, u16* __restrict__ y, int n4){
  int i = blockIdx.x * 256 + threadIdx.x;
  if (i < n4){
    float4 v = ((const float4*)x)[i];
    ushort4 o;
    o.x = f2bf(v.x); o.y = f2bf(v.y); o.z = f2bf(v.z); o.w = f2bf(v.w);
    ((ushort4*)y)[i] = o;
  }
}

// W [1024,1024] f32 -> Wt [1024,1024] bf16 transposed (Wt[n][k] = W[k][n])
__global__ __launch_bounds__(256) void k_transpose(const float* __restrict__ W, u16* __restrict__ Wt){
  __shared__ float t[64][65];
  const int n0 = blockIdx.x * 64, k0 = blockIdx.y * 64;
  const int tid = threadIdx.x;
  #pragma unroll
  for (int i = 0; i < 16; i++){
    int e = i * 256 + tid; int r = e >> 6, c = e & 63;
    t[r][c] = W[(long)(k0 + r) * 1024 + n0 + c];
  }
  __syncthreads();
  #pragma unroll
  for (int i = 0; i < 16; i++){
    int e = i * 256 + tid; int r = e >> 6, c = e & 63;
    Wt[(long)(n0 + r) * 1024 + k0 + c] = f2bf(t[c][r]);
  }
}

// LayerNorm rows of rel_emb [512,1024] -> bf16
__global__ __launch_bounds__(256) void k_ln(const float* __restrict__ x, const float* __restrict__ g,
                                            const float* __restrict__ b, u16* __restrict__ y){
  const int row = blockIdx.x, tid = threadIdx.x;
  float4 v = ((const float4*)(x + (long)row * 1024))[tid];
  float s  = v.x + v.y + v.z + v.w;
  float s2 = v.x*v.x + v.y*v.y + v.z*v.z + v.w*v.w;
  #pragma unroll
  for (int o = 1; o < 64; o <<= 1){ s += __shfl_xor(s, o); s2 += __shfl_xor(s2, o); }
  __shared__ float red[8];
  if ((tid & 63) == 0){ red[(tid >> 6) * 2] = s; red[(tid >> 6) * 2 + 1] = s2; }
  __syncthreads();
  s  = red[0] + red[2] + red[4] + red[6];
  s2 = red[1] + red[3] + red[5] + red[7];
  float mu  = s * (1.f / 1024.f);
  float var = s2 * (1.f / 1024.f) - mu * mu;
  float rs  = rsqrtf(var + 1e-5f);
  float4 gg = ((const float4*)g)[tid];
  float4 bb = ((const float4*)b)[tid];
  ushort4 o;
  o.x = f2bf((v.x - mu) * rs * gg.x + bb.x);
  o.y = f2bf((v.y - mu) * rs * gg.y + bb.y);
  o.z = f2bf((v.z - mu) * rs * gg.z + bb.z);
  o.w = f2bf((v.w - mu) * rs * gg.w + bb.w);
  ((ushort4*)(y + (long)row * 1024))[tid] = o;
}

// bucket index table: idx(delta) for delta in [-1023,1023], stored at [delta+1023]
__global__ void k_idx(u16* __restrict__ t){
  int i = blockIdx.x * 256 + threadIdx.x;
  if (i >= 2047) return;
  int delta = i - 1023;
  int b;
  if (delta >= -128 && delta <= 128) b = delta;
  else {
    float a = (float)(delta < 0 ? -delta : delta);
    float lp = ceilf(logf(a * (1.0f / 128.0f)) / logf(511.0f / 128.0f) * 127.0f) + 128.0f;
    b = (int)lp;
    if (delta < 0) b = -b;
  }
  int idx = b + 256;
  idx = idx < 0 ? 0 : (idx > 511 ? 511 : idx);
  t[i] = (u16)idx;
}

// ---------------- MFMA GEMM: C[M,N] = A[M,K] @ Bt[N,K]^T (+bias) ----------------
// A row-major bf16 (lda), Bt row-major [N,K] bf16 (ldb). 128x128 tile, BK=64,
// 256 thr / 4 waves, global_load_lds w16 staging, XOR-swizzled LDS.
// MODE: 0 f32 rowmajor(ldc=N)  1 bf16 [B,H,S,hd]  2 bf16 [B,H,hd,S]
//       3 bf16 [H,512,hd]      4 bf16 batched rowmajor
template<int MODE>
__global__ __launch_bounds__(256) void k_gemm(
    const u16* __restrict__ A, const u16* __restrict__ Bt,
    const float* __restrict__ bias, void* __restrict__ C,
    int M, int N, int K, int lda, int ldb,
    long strideA, long strideB, int modB)
{
  __shared__ __attribute__((aligned(16))) u16 As[128 * 64];
  __shared__ __attribute__((aligned(16))) u16 Bs[128 * 64];
  const int z = blockIdx.z;
  const u16* Ab = A + (long)z * strideA;
  const u16* Bb = Bt + (long)(z % modB) * strideB;
  const int m0 = blockIdx.y * 128, n0 = blockIdx.x * 128;
  const int tid = threadIdx.x, lane = tid & 63, w = tid >> 6;
  const int wm = (w >> 1) * 64, wn = (w & 1) * 64;
  floatx4 acc[4][4];
  #pragma unroll
  for (int i = 0; i < 4; i++)
    #pragma unroll
    for (int j = 0; j < 4; j++) acc[i][j] = (floatx4){0.f, 0.f, 0.f, 0.f};

  const int r8 = lane >> 3;
  const int cswz = ((lane & 7) ^ r8) << 4;   // swizzled source byte-offset within 128B row

  for (int kt = 0; kt < K; kt += 64){
    #pragma unroll
    for (int c = 0; c < 4; c++){
      int row = (c * 4 + w) * 8 + r8;
      const char* ga = (const char*)(Ab + (long)(m0 + row) * lda + kt) + cswz;
      __builtin_amdgcn_global_load_lds((gas_ptr)ga, (las_ptr)((char*)As + (c * 4 + w) * 1024), 16, 0, 0);
      const char* gb = (const char*)(Bb + (long)(n0 + row) * ldb + kt) + cswz;
      __builtin_amdgcn_global_load_lds((gas_ptr)gb, (las_ptr)((char*)Bs + (c * 4 + w) * 1024), 16, 0, 0);
    }
    __syncthreads();
    short8_t af[2][4], bfr[2][4];
    #pragma unroll
    for (int kk = 0; kk < 2; kk++){
      #pragma unroll
      for (int i = 0; i < 4; i++){
        int ra = wm + i * 16 + (lane & 15);
        af[kk][i] = *(const short8_t*)((const char*)As + ra * 128 + ((kk * 64 + ((lane >> 4) << 4)) ^ ((ra & 7) << 4)));
        int rb = wn + i * 16 + (lane & 15);
        bfr[kk][i] = *(const short8_t*)((const char*)Bs + rb * 128 + ((kk * 64 + ((lane >> 4) << 4)) ^ ((rb & 7) << 4)));
      }
    }
    #pragma unroll
    for (int i = 0; i < 4; i++)
      #pragma unroll
      for (int j = 0; j < 4; j++){
        acc[i][j] = __builtin_amdgcn_mfma_f32_16x16x32_bf16(af[0][i], bfr[0][j], acc[i][j], 0, 0, 0);
        acc[i][j] = __builtin_amdgcn_mfma_f32_16x16x32_bf16(af[1][i], bfr[1][j], acc[i][j], 0, 0, 0);
      }
    __syncthreads();
  }

  #pragma unroll
  for (int i = 0; i < 4; i++){
    #pragma unroll
    for (int j = 0; j < 4; j++){
      #pragma unroll
      for (int r = 0; r < 4; r++){
        int m = m0 + wm + i * 16 + ((lane >> 4) << 2) + r;
        int n = n0 + wn + j * 16 + (lane & 15);
        float v = acc[i][j][r] + (bias ? bias[n] : 0.f);
        if (MODE == 0){
          ((float*)C)[(long)m * N + n] = v;
        } else if (MODE == 1){
          int b = m >> 10, s = m & 1023, h = n >> 6, d = n & 63;
          ((u16*)C)[((long)(b * 16 + h) * 1024 + s) * 64 + d] = f2bf(v);
        } else if (MODE == 2){
          int b = m >> 10, s = m & 1023, h = n >> 6, d = n & 63;
          ((u16*)C)[((long)(b * 16 + h) * 64 + d) * 1024 + s] = f2bf(v);
        } else if (MODE == 3){
          int h = n >> 6, d = n & 63;
          ((u16*)C)[((long)h * 512 + m) * 64 + d] = f2bf(v);
        } else {
          ((u16*)C)[(long)z * ((long)M * N) + (long)m * N + n] = f2bf(v);
        }
      }
    }
  }
}

// ---------------- fused attention ----------------
// grid (32 s-blocks, 64 bh). 128 threads = 2 waves; each wave owns 16 rows.
// Q [B,H,S,64], Kt [B,H,S,64], Vt [B,H,64,S], c2p/p2c [B,H,S,512] all bf16.
__global__ __launch_bounds__(128) void k_attn(
    const u16* __restrict__ Q, const u16* __restrict__ Kt,
    const u16* __restrict__ Vt, const u16* __restrict__ c2p,
    const u16* __restrict__ p2c, const u16* __restrict__ idxt,
    u16* __restrict__ ctx)
{
  __shared__ __attribute__((aligned(16))) u16 sc[32 * 1024];  // 64KB swizzled scores
  const int sb = blockIdx.x, bh = blockIdx.y;
  const int s0 = sb * 32;
  const u16* Qb   = Q   + (long)bh * 65536;
  const u16* Kb   = Kt  + (long)bh * 65536;
  const u16* Vb   = Vt  + (long)bh * 65536;
  const u16* c2pb = c2p + (long)bh * 524288;
  const u16* p2cb = p2c + (long)bh * 524288;
  const int tid = threadIdx.x, lane = tid & 63, w = tid >> 6;
  const int l15 = lane & 15, lq = lane >> 4;

  short8_t qf[2];
  {
    const u16* p = Qb + (long)(s0 + w * 16 + l15) * 64 + (lq << 3);
    qf[0] = *(const short8_t*)p;
    qf[1] = *(const short8_t*)(p + 32);
  }
  const float sA = 0.07216878365f;  // 1/sqrt(192)
  const float sB = 0.08838834765f;  // 1/sqrt(128)

  // phase 1: scores + bias -> LDS (bf16, swizzled)
  for (int kt0 = 0; kt0 < 1024; kt0 += 128){
    floatx4 a8[8];
    #pragma unroll
    for (int nf = 0; nf < 8; nf++) a8[nf] = (floatx4){0.f, 0.f, 0.f, 0.f};
    #pragma unroll
    for (int nf = 0; nf < 8; nf++){
      const u16* kp = Kb + (long)(kt0 + nf * 16 + l15) * 64 + (lq << 3);
      short8_t k0v = *(const short8_t*)kp;
      short8_t k1v = *(const short8_t*)(kp + 32);
      a8[nf] = __builtin_amdgcn_mfma_f32_16x16x32_bf16(qf[0], k0v, a8[nf], 0, 0, 0);
      a8[nf] = __builtin_amdgcn_mfma_f32_16x16x32_bf16(qf[1], k1v, a8[nf], 0, 0, 0);
    }
    #pragma unroll
    for (int nf = 0; nf < 8; nf++){
      int k = kt0 + nf * 16 + l15;
      #pragma unroll
      for (int r = 0; r < 4; r++){
        int sl = w * 16 + (lq << 2) + r;
        int s  = s0 + sl;
        int idx = idxt[s - k + 1023];
        float g = bf2f(c2pb[(long)s * 512 + idx]) + bf2f(p2cb[(long)k * 512 + idx]);
        float v = a8[nf][r] * sA + g * sB;
        int byte_ = sl * 2048 + ((k * 2) ^ ((sl & 7) << 4));
        sc[byte_ >> 1] = f2bf(v);
      }
    }
  }
  __syncthreads();

  // phase 2: softmax per row (rows wave-private); unnormalized exp back to LDS,
  // 1/sum kept in registers (redistributed by shuffle later).
  float rinv;
  {
    const int rl = w * 16 + (lane >> 2);
    const int q4 = lane & 3;
    const int swz = (rl & 7) << 4;
    const char* rowp = (const char*)sc + rl * 2048;
    float mx = -3.0e38f;
    for (int i = 0; i < 32; i++){
      short8_t v = *(const short8_t*)(rowp + ((q4 * 512 + i * 16) ^ swz));
      #pragma unroll
      for (int j = 0; j < 8; j++) mx = fmaxf(mx, bf2f((u16)v[j]));
    }
    mx = fmaxf(mx, __shfl_xor(mx, 1));
    mx = fmaxf(mx, __shfl_xor(mx, 2));
    float sum = 0.f;
    for (int i = 0; i < 32; i++){
      char* p = (char*)sc + rl * 2048 + ((q4 * 512 + i * 16) ^ swz);
      short8_t v = *(short8_t*)p;
      short8_t e;
      #pragma unroll
      for (int j = 0; j < 8; j++){
        float ev = __expf(bf2f((u16)v[j]) - mx);
        sum += ev;
        e[j] = (short)f2bf(ev);
      }
      *(short8_t*)p = e;
    }
    sum += __shfl_xor(sum, 1);
    sum += __shfl_xor(sum, 2);
    rinv = 1.f / sum;   // every lane: 1/sum of row (w*16 + lane/4)
  }
  __syncthreads();

  // phase 3: O = P @ V
  floatx4 o4[4];
  #pragma unroll
  for (int nf = 0; nf < 4; nf++) o4[nf] = (floatx4){0.f, 0.f, 0.f, 0.f};
  for (int kt0 = 0; kt0 < 1024; kt0 += 128){
    #pragma unroll
    for (int kk = 0; kk < 4; kk++){
      int rr = w * 16 + l15;
      int kb = (kt0 + kk * 32 + (lq << 3)) * 2;
      short8_t pf = *(const short8_t*)((const char*)sc + rr * 2048 + (kb ^ ((rr & 7) << 4)));
      #pragma unroll
      for (int nf = 0; nf < 4; nf++){
        const u16* vp = Vb + (long)(nf * 16 + l15) * 1024 + kt0 + kk * 32 + (lq << 3);
        short8_t vf = *(const short8_t*)vp;
        o4[nf] = __builtin_amdgcn_mfma_f32_16x16x32_bf16(pf, vf, o4[nf], 0, 0, 0);
      }
    }
  }
  const int b = bh >> 4, h = bh & 15;
  #pragma unroll
  for (int nf = 0; nf < 4; nf++){
    #pragma unroll
    for (int r = 0; r < 4; r++){
      int sl = w * 16 + (lq << 2) + r;
      float ri = __shfl(rinv, ((lq << 2) + r) << 2);
      float val = o4[nf][r] * ri;
      long oi = ((long)b * 1024 + (s0 + sl)) * 1024 + h * 64 + nf * 16 + l15;
      ctx[oi] = f2bf(val);
    }
  }
}

// ---------------- launch ----------------
extern "C" void kernel_launch(void* const* d_in, const int* in_sizes, int n_in,
                              void* d_out, int out_size, void* d_ws, size_t ws_size,
                              hipStream_t stream){
  const float* hs  = (const float*)d_in[0];
  const float* Wq  = (const float*)d_in[1];
  const float* bq  = (const float*)d_in[2];
  const float* Wk  = (const float*)d_in[3];
  const float* bk  = (const float*)d_in[4];
  const float* Wv  = (const float*)d_in[5];
  const float* bv  = (const float*)d_in[6];
  const float* Wo  = (const float*)d_in[7];
  const float* bo  = (const float*)d_in[8];
  const float* rel = (const float*)d_in[9];
  const float* lng = (const float*)d_in[10];
  const float* lnb = (const float*)d_in[11];
  const float* Wpk = (const float*)d_in[12];
  const float* bpk = (const float*)d_in[13];
  const float* Wpq = (const float*)d_in[14];
  const float* bpq = (const float*)d_in[15];

  char* ws = (char*)d_ws;
  size_t off = 0;
  auto alloc = [&](size_t bytes){ size_t o = off; off += (bytes + 255) & ~(size_t)255; return o; };
  u16* h_bf  = (u16*)(ws + alloc(4096UL * 1024 * 2));
  u16* Wq_t  = (u16*)(ws + alloc(1024UL * 1024 * 2));
  u16* Wk_t  = (u16*)(ws + alloc(1024UL * 1024 * 2));
  u16* Wv_t  = (u16*)(ws + alloc(1024UL * 1024 * 2));
  u16* Wo_t  = (u16*)(ws + alloc(1024UL * 1024 * 2));
  u16* Wpk_t = (u16*)(ws + alloc(1024UL * 1024 * 2));
  u16* Wpq_t = (u16*)(ws + alloc(1024UL * 1024 * 2));
  u16* re_bf = (u16*)(ws + alloc(512UL * 1024 * 2));
  u16* Qd    = (u16*)(ws + alloc(64UL * 1024 * 64 * 2));
  u16* Kd    = (u16*)(ws + alloc(64UL * 1024 * 64 * 2));
  u16* Vtd   = (u16*)(ws + alloc(64UL * 64 * 1024 * 2));
  u16* posk  = (u16*)(ws + alloc(16UL * 512 * 64 * 2));
  u16* posq  = (u16*)(ws + alloc(16UL * 512 * 64 * 2));
  u16* c2p   = (u16*)(ws + alloc(64UL * 1024 * 512 * 2));
  u16* p2c   = (u16*)(ws + alloc(64UL * 1024 * 512 * 2));
  u16* ctx   = (u16*)(ws + alloc(4096UL * 1024 * 2));
  u16* idxt  = (u16*)(ws + alloc(2048UL * 2));

  k_conv<<<4096, 256, 0, stream>>>(hs, h_bf, 1048576);
  dim3 tg(16, 16);
  k_transpose<<<tg, 256, 0, stream>>>(Wq,  Wq_t);
  k_transpose<<<tg, 256, 0, stream>>>(Wk,  Wk_t);
  k_transpose<<<tg, 256, 0, stream>>>(Wv,  Wv_t);
  k_transpose<<<tg, 256, 0, stream>>>(Wo,  Wo_t);
  k_transpose<<<tg, 256, 0, stream>>>(Wpk, Wpk_t);
  k_transpose<<<tg, 256, 0, stream>>>(Wpq, Wpq_t);
  k_ln<<<512, 256, 0, stream>>>(rel, lng, lnb, re_bf);
  k_idx<<<8, 256, 0, stream>>>(idxt);

  // projections
  k_gemm<1><<<dim3(8, 32, 1), 256, 0, stream>>>(h_bf, Wq_t, bq, Qd,  4096, 1024, 1024, 1024, 1024, 0, 0, 1);
  k_gemm<1><<<dim3(8, 32, 1), 256, 0, stream>>>(h_bf, Wk_t, bk, Kd,  4096, 1024, 1024, 1024, 1024, 0, 0, 1);
  k_gemm<2><<<dim3(8, 32, 1), 256, 0, stream>>>(h_bf, Wv_t, bv, Vtd, 4096, 1024, 1024, 1024, 1024, 0, 0, 1);
  k_gemm<3><<<dim3(8, 4, 1),  256, 0, stream>>>(re_bf, Wpk_t, bpk, posk, 512, 1024, 1024, 1024, 1024, 0, 0, 1);
  k_gemm<3><<<dim3(8, 4, 1),  256, 0, stream>>>(re_bf, Wpq_t, bpq, posq, 512, 1024, 1024, 1024, 1024, 0, 0, 1);
  // c2p = Q @ posk^T, p2c = K @ posq^T  (batched over bh, K=64)
  k_gemm<4><<<dim3(4, 8, 64), 256, 0, stream>>>(Qd, posk, nullptr, c2p, 1024, 512, 64, 64, 64, 65536, 32768, 16);
  k_gemm<4><<<dim3(4, 8, 64), 256, 0, stream>>>(Kd, posq, nullptr, p2c, 1024, 512, 64, 64, 64, 65536, 32768, 16);

  k_attn<<<dim3(32, 64), 128, 0, stream>>>(Qd, Kd, Vtd, c2p, p2c, idxt, ctx);

  k_gemm<0><<<dim3(8, 32, 1), 256, 0, stream>>>(ctx, Wo_t, bo, d_out, 4096, 1024, 1024, 1024, 1024, 0, 0, 1);
}

// Round 3
// 418.532 us; speedup vs baseline: 1.2642x; 1.2642x over previous
//
#include <hip/hip_runtime.h>

typedef unsigned short u16;
typedef __attribute__((ext_vector_type(8))) short short8_t;
typedef __attribute__((ext_vector_type(4))) float floatx4;

typedef const void __attribute__((address_space(1)))* gas_ptr;
typedef void __attribute__((address_space(3)))* las_ptr;

__device__ __forceinline__ float bf2f(u16 u){
  union { unsigned i; float f; } v; v.i = ((unsigned)u) << 16; return v.f;
}
__device__ __forceinline__ u16 f2bf(float x){
  unsigned u = __float_as_uint(x);
  return (u16)((u + 0x7FFFu + ((u >> 16) & 1u)) >> 16);
}

// ---------------- small prep kernels ----------------

__global__ __launch_bounds__(256) void k_conv(const float* __restrict__ x, u16* __restrict__ y, int n4){
  int i = blockIdx.x * 256 + threadIdx.x;
  if (i < n4){
    float4 v = ((const float4*)x)[i];
    ushort4 o;
    o.x = f2bf(v.x); o.y = f2bf(v.y); o.z = f2bf(v.z); o.w = f2bf(v.w);
    ((ushort4*)y)[i] = o;
  }
}

// 6 weight matrices [1024,1024] f32 -> bf16 transposed, z picks the matrix
__global__ __launch_bounds__(256) void k_transpose6(
    const float* __restrict__ s0, const float* __restrict__ s1, const float* __restrict__ s2,
    const float* __restrict__ s3, const float* __restrict__ s4, const float* __restrict__ s5,
    u16* __restrict__ dst){
  __shared__ float t[64][65];
  const float* W;
  switch (blockIdx.z){
    case 0: W = s0; break; case 1: W = s1; break; case 2: W = s2; break;
    case 3: W = s3; break; case 4: W = s4; break; default: W = s5; break;
  }
  u16* Wt = dst + (long)blockIdx.z * 1048576;
  const int n0 = blockIdx.x * 64, k0 = blockIdx.y * 64;
  const int tid = threadIdx.x;
  #pragma unroll
  for (int i = 0; i < 16; i++){
    int e = i * 256 + tid; int r = e >> 6, c = e & 63;
    t[r][c] = W[(long)(k0 + r) * 1024 + n0 + c];
  }
  __syncthreads();
  #pragma unroll
  for (int i = 0; i < 16; i++){
    int e = i * 256 + tid; int r = e >> 6, c = e & 63;
    Wt[(long)(n0 + r) * 1024 + k0 + c] = f2bf(t[c][r]);
  }
}

// LayerNorm rows of rel_emb [512,1024] -> bf16
__global__ __launch_bounds__(256) void k_ln(const float* __restrict__ x, const float* __restrict__ g,
                                            const float* __restrict__ b, u16* __restrict__ y){
  const int row = blockIdx.x, tid = threadIdx.x;
  float4 v = ((const float4*)(x + (long)row * 1024))[tid];
  float s  = v.x + v.y + v.z + v.w;
  float s2 = v.x*v.x + v.y*v.y + v.z*v.z + v.w*v.w;
  #pragma unroll
  for (int o = 1; o < 64; o <<= 1){ s += __shfl_xor(s, o); s2 += __shfl_xor(s2, o); }
  __shared__ float red[8];
  if ((tid & 63) == 0){ red[(tid >> 6) * 2] = s; red[(tid >> 6) * 2 + 1] = s2; }
  __syncthreads();
  s  = red[0] + red[2] + red[4] + red[6];
  s2 = red[1] + red[3] + red[5] + red[7];
  float mu  = s * (1.f / 1024.f);
  float var = s2 * (1.f / 1024.f) - mu * mu;
  float rs  = rsqrtf(var + 1e-5f);
  float4 gg = ((const float4*)g)[tid];
  float4 bb = ((const float4*)b)[tid];
  ushort4 o;
  o.x = f2bf((v.x - mu) * rs * gg.x + bb.x);
  o.y = f2bf((v.y - mu) * rs * gg.y + bb.y);
  o.z = f2bf((v.z - mu) * rs * gg.z + bb.z);
  o.w = f2bf((v.w - mu) * rs * gg.w + bb.w);
  ((ushort4*)(y + (long)row * 1024))[tid] = o;
}

// bucket index table: idx(delta) for delta in [-1023,1023], stored at [delta+1023]
__global__ void k_idx(u16* __restrict__ t){
  int i = blockIdx.x * 256 + threadIdx.x;
  if (i >= 2047) return;
  int delta = i - 1023;
  int b;
  if (delta >= -128 && delta <= 128) b = delta;
  else {
    float a = (float)(delta < 0 ? -delta : delta);
    float lp = ceilf(logf(a * (1.0f / 128.0f)) / logf(511.0f / 128.0f) * 127.0f) + 128.0f;
    b = (int)lp;
    if (delta < 0) b = -b;
  }
  int idx = b + 256;
  idx = idx < 0 ? 0 : (idx > 511 ? 511 : idx);
  t[i] = (u16)idx;
}

// ---------------- MFMA GEMM: C[M,N] = A[M,K] @ Bt[N,K]^T (+bias) ----------------
// MODE: 0 f32 rowmajor   1 bf16 [B,H,S,hd]   2 bf16 [B,H,hd,S] via LDS-bounce
//       3 bf16 [H,512,hd]   4 bf16 batched rowmajor
template<int MODE>
__global__ __launch_bounds__(256) void k_gemm(
    const u16* __restrict__ A, const u16* __restrict__ Bt,
    const float* __restrict__ bias, void* __restrict__ C,
    int M, int N, int K, int lda, int ldb,
    long strideA, long strideB, int modA, int modB)
{
  __shared__ __attribute__((aligned(16))) u16 smem[16384];   // As 8192 | Bs 8192 elems
  u16* As = smem;
  u16* Bs = smem + 8192;
  const int z = blockIdx.z;
  const u16* Ab = A + (long)(z % modA) * strideA;
  const u16* Bb = Bt + (long)(z % modB) * strideB;
  const int m0 = blockIdx.y * 128, n0 = blockIdx.x * 128;
  const int tid = threadIdx.x, lane = tid & 63, w = tid >> 6;
  const int wm = (w >> 1) * 64, wn = (w & 1) * 64;
  floatx4 acc[4][4];
  #pragma unroll
  for (int i = 0; i < 4; i++)
    #pragma unroll
    for (int j = 0; j < 4; j++) acc[i][j] = (floatx4){0.f, 0.f, 0.f, 0.f};

  const int r8 = lane >> 3;
  const int cswz = ((lane & 7) ^ r8) << 4;

  for (int kt = 0; kt < K; kt += 64){
    #pragma unroll
    for (int c = 0; c < 4; c++){
      int row = (c * 4 + w) * 8 + r8;
      const char* ga = (const char*)(Ab + (long)(m0 + row) * lda + kt) + cswz;
      __builtin_amdgcn_global_load_lds((gas_ptr)ga, (las_ptr)((char*)As + (c * 4 + w) * 1024), 16, 0, 0);
      const char* gb = (const char*)(Bb + (long)(n0 + row) * ldb + kt) + cswz;
      __builtin_amdgcn_global_load_lds((gas_ptr)gb, (las_ptr)((char*)Bs + (c * 4 + w) * 1024), 16, 0, 0);
    }
    __syncthreads();
    short8_t af[2][4], bfr[2][4];
    #pragma unroll
    for (int kk = 0; kk < 2; kk++){
      #pragma unroll
      for (int i = 0; i < 4; i++){
        int ra = wm + i * 16 + (lane & 15);
        af[kk][i] = *(const short8_t*)((const char*)As + ra * 128 + ((kk * 64 + ((lane >> 4) << 4)) ^ ((ra & 7) << 4)));
        int rb = wn + i * 16 + (lane & 15);
        bfr[kk][i] = *(const short8_t*)((const char*)Bs + rb * 128 + ((kk * 64 + ((lane >> 4) << 4)) ^ ((rb & 7) << 4)));
      }
    }
    #pragma unroll
    for (int i = 0; i < 4; i++)
      #pragma unroll
      for (int j = 0; j < 4; j++){
        acc[i][j] = __builtin_amdgcn_mfma_f32_16x16x32_bf16(af[0][i], bfr[0][j], acc[i][j], 0, 0, 0);
        acc[i][j] = __builtin_amdgcn_mfma_f32_16x16x32_bf16(af[1][i], bfr[1][j], acc[i][j], 0, 0, 0);
      }
    __syncthreads();
  }

  if (MODE == 2){
    // transpose through LDS: write acc as [n_local 128][m_local 128] bf16 (swizzled)
    #pragma unroll
    for (int i = 0; i < 4; i++){
      #pragma unroll
      for (int j = 0; j < 4; j++){
        #pragma unroll
        for (int r = 0; r < 4; r++){
          int ml = wm + i * 16 + ((lane >> 4) << 2) + r;
          int nl = wn + j * 16 + (lane & 15);
          float v = acc[i][j][r] + (bias ? bias[n0 + nl] : 0.f);
          int byte_ = nl * 256 + ((ml * 2) ^ ((nl & 7) << 4));
          *(u16*)((char*)smem + byte_) = f2bf(v);
        }
      }
    }
    __syncthreads();
    // stream out coalesced: Vt[((b*16+h)*64 + d)*1024 + s]
    #pragma unroll
    for (int rr = 0; rr < 8; rr++){
      int nl = rr * 16 + (tid >> 4);
      int n  = n0 + nl;
      int mc = tid & 15;
      short8_t vv = *(const short8_t*)((const char*)smem + nl * 256 + ((mc * 16) ^ ((nl & 7) << 4)));
      int m = m0 + mc * 8;
      long base = ((long)((m >> 10) * 16 + (n >> 6)) * 64 + (n & 63)) * 1024 + (m & 1023);
      *(short8_t*)((u16*)C + base) = vv;
    }
    return;
  }

  #pragma unroll
  for (int i = 0; i < 4; i++){
    #pragma unroll
    for (int j = 0; j < 4; j++){
      #pragma unroll
      for (int r = 0; r < 4; r++){
        int m = m0 + wm + i * 16 + ((lane >> 4) << 2) + r;
        int n = n0 + wn + j * 16 + (lane & 15);
        float v = acc[i][j][r] + (bias ? bias[n] : 0.f);
        if (MODE == 0){
          ((float*)C)[(long)m * N + n] = v;
        } else if (MODE == 1){
          int b = m >> 10, s = m & 1023, h = n >> 6, d = n & 63;
          ((u16*)C)[((long)(b * 16 + h) * 1024 + s) * 64 + d] = f2bf(v);
        } else if (MODE == 3){
          int h = n >> 6, d = n & 63;
          ((u16*)C)[((long)h * 512 + m) * 64 + d] = f2bf(v);
        } else {
          ((u16*)C)[(long)z * ((long)M * N) + (long)m * N + n] = f2bf(v);
        }
      }
    }
  }
}

// ---------------- fused attention (flash-style, no-max softmax) ----------------
// grid 1024 blocks (xcd-chunked -> (bh, sb)), 256 thr = 4 waves, 16 s-rows/wave.
// Q,K [B,H,S,64]; Vt [B,H,64,S]; c2p [B,H,S,512]; p2c [B,H,S,512]; all bf16.
__global__ __launch_bounds__(256, 4) void k_attn(
    const u16* __restrict__ Q, const u16* __restrict__ K, const u16* __restrict__ Vt,
    const u16* __restrict__ c2p, const u16* __restrict__ p2c,
    const u16* __restrict__ idxt, u16* __restrict__ ctx)
{
  __shared__ __attribute__((aligned(16))) u16 Ks[2][4096];   // [64k][64d] swizzled
  __shared__ __attribute__((aligned(16))) u16 Vs[2][4096];   // [64d][64k] swizzled (V^T)
  __shared__ __attribute__((aligned(16))) u16 Ps[4][1024];   // per-wave [16s][64k] swizzled
  const int flat0 = blockIdx.x;
  const int flat = (flat0 & 7) * 128 + (flat0 >> 3);   // xcd-chunked
  const int bh = flat >> 4, sb = flat & 15;
  const int tid = threadIdx.x, lane = tid & 63, w = tid >> 6;
  const int s15 = lane & 15, g = lane >> 4;
  const int s_row = sb * 64 + w * 16 + s15;
  const u16* Qb = Q   + (long)bh * 65536;
  const u16* Kg = K   + (long)bh * 65536;
  const u16* Vg = Vt  + (long)bh * 65536;
  const u16* c2row  = c2p + (long)bh * 524288 + (long)s_row * 512;  // + idx
  const u16* p2base = p2c + (long)bh * 524288;                     // + k*512 + idx
  const u16* ixbase = idxt + s_row + 1023;                         // [-k]

  short8_t qf0 = *(const short8_t*)(Qb + (long)s_row * 64 + g * 8);
  short8_t qf1 = *(const short8_t*)(Qb + (long)s_row * 64 + 32 + g * 8);

  const int srow8  = lane >> 3;
  const int schunk = (lane & 7) ^ (srow8 & 7);
  const float sA = 0.07216878365f;   // 1/sqrt(192)
  const float sB = 0.08838834765f;   // 1/sqrt(128)

  auto STAGE = [&](int buf, int kt){
    #pragma unroll
    for (int ii = 0; ii < 2; ii++){
      int i = w * 2 + ii;
      int row = i * 8 + srow8;
      __builtin_amdgcn_global_load_lds(
        (gas_ptr)((const char*)(Kg + (long)(kt + row) * 64) + schunk * 16),
        (las_ptr)((char*)&Ks[buf][0] + i * 1024), 16, 0, 0);
      __builtin_amdgcn_global_load_lds(
        (gas_ptr)((const char*)(Vg + (long)row * 1024 + kt) + schunk * 16),
        (las_ptr)((char*)&Vs[buf][0] + i * 1024), 16, 0, 0);
    }
  };

  STAGE(0, 0);

  float rowsum = 0.f;
  floatx4 oacc[4];
  #pragma unroll
  for (int dt = 0; dt < 4; dt++) oacc[dt] = (floatx4){0.f, 0.f, 0.f, 0.f};

  const int psw = (s15 & 7) << 4;
  char* Pw = (char*)&Ps[w][0];

  for (int t = 0; t < 16; t++){
    const int buf = t & 1;
    const int kt = t * 64;
    __syncthreads();
    if (t < 15) STAGE(buf ^ 1, kt + 64);

    // QK^T swapped: acc[T] = C[k-local 16][s 16], lane: col s=s15, rows k=g*4+r
    floatx4 a[4];
    #pragma unroll
    for (int T = 0; T < 4; T++){
      int row = T * 16 + s15;
      const char* rp = (const char*)&Ks[buf][0] + row * 128;
      int sw = (row & 7) << 4;
      short8_t k0 = *(const short8_t*)(rp + ((g * 16) ^ sw));
      short8_t k1 = *(const short8_t*)(rp + ((64 + g * 16) ^ sw));
      floatx4 acc = (floatx4){0.f, 0.f, 0.f, 0.f};
      acc = __builtin_amdgcn_mfma_f32_16x16x32_bf16(k0, qf0, acc, 0, 0, 0);
      acc = __builtin_amdgcn_mfma_f32_16x16x32_bf16(k1, qf1, acc, 0, 0, 0);
      a[T] = acc;
    }

    // bias gather + exp + pack (RNE f2bf) -> Ps; rowsum from ROUNDED values
    #pragma unroll
    for (int T = 0; T < 4; T++){
      int kb = kt + T * 16 + g * 4;
      float e0, e1, e2, e3;
      {
        int k = kb;
        int idx = (int)ixbase[-k];
        float b1 = bf2f(c2row[idx]);
        float b2 = bf2f(p2base[(k << 9) + idx]);
        e0 = __expf(a[T][0] * sA + (b1 + b2) * sB);
      }
      {
        int k = kb + 1;
        int idx = (int)ixbase[-k];
        float b1 = bf2f(c2row[idx]);
        float b2 = bf2f(p2base[(k << 9) + idx]);
        e1 = __expf(a[T][1] * sA + (b1 + b2) * sB);
      }
      {
        int k = kb + 2;
        int idx = (int)ixbase[-k];
        float b1 = bf2f(c2row[idx]);
        float b2 = bf2f(p2base[(k << 9) + idx]);
        e2 = __expf(a[T][2] * sA + (b1 + b2) * sB);
      }
      {
        int k = kb + 3;
        int idx = (int)ixbase[-k];
        float b1 = bf2f(c2row[idx]);
        float b2 = bf2f(p2base[(k << 9) + idx]);
        e3 = __expf(a[T][3] * sA + (b1 + b2) * sB);
      }
      u16 p0 = f2bf(e0), p1 = f2bf(e1), p2v = f2bf(e2), p3 = f2bf(e3);
      rowsum += (bf2f(p0) + bf2f(p1)) + (bf2f(p2v) + bf2f(p3));
      uint2 pk2;
      pk2.x = (unsigned)p0  | ((unsigned)p1 << 16);
      pk2.y = (unsigned)p2v | ((unsigned)p3 << 16);
      int byte_ = s15 * 128 + ((T * 32 + g * 8) ^ psw);
      *(uint2*)(Pw + byte_) = pk2;
    }

    // PV: O[s, d] += P[s,:] V[:, d]
    #pragma unroll
    for (int M = 0; M < 2; M++){
      short8_t pf = *(const short8_t*)(Pw + (s15 * 128 + ((M * 64 + g * 16) ^ psw)));
      #pragma unroll
      for (int dt = 0; dt < 4; dt++){
        int drow = dt * 16 + s15;
        short8_t vf = *(const short8_t*)((const char*)&Vs[buf][0] + drow * 128 + ((M * 64 + g * 16) ^ ((drow & 7) << 4)));
        oacc[dt] = __builtin_amdgcn_mfma_f32_16x16x32_bf16(pf, vf, oacc[dt], 0, 0, 0);
      }
    }
  }

  rowsum += __shfl_xor(rowsum, 16);
  rowsum += __shfl_xor(rowsum, 32);
  float rinv = 1.f / rowsum;

  const int b = bh >> 4, h = bh & 15;
  #pragma unroll
  for (int r = 0; r < 4; r++){
    float ri = __shfl(rinv, g * 4 + r);
    int s_out = sb * 64 + w * 16 + g * 4 + r;
    #pragma unroll
    for (int dt = 0; dt < 4; dt++){
      long oi = ((long)b * 1024 + s_out) * 1024 + h * 64 + dt * 16 + s15;
      ctx[oi] = f2bf(oacc[dt][r] * ri);
    }
  }
}

// ---------------- launch ----------------
extern "C" void kernel_launch(void* const* d_in, const int* in_sizes, int n_in,
                              void* d_out, int out_size, void* d_ws, size_t ws_size,
                              hipStream_t stream){
  const float* hs  = (const float*)d_in[0];
  const float* Wq  = (const float*)d_in[1];
  const float* bq  = (const float*)d_in[2];
  const float* Wk  = (const float*)d_in[3];
  const float* bk  = (const float*)d_in[4];
  const float* Wv  = (const float*)d_in[5];
  const float* bv  = (const float*)d_in[6];
  const float* Wo  = (const float*)d_in[7];
  const float* bo  = (const float*)d_in[8];
  const float* rel = (const float*)d_in[9];
  const float* lng = (const float*)d_in[10];
  const float* lnb = (const float*)d_in[11];
  const float* Wpk = (const float*)d_in[12];
  const float* bpk = (const float*)d_in[13];
  const float* Wpq = (const float*)d_in[14];
  const float* bpq = (const float*)d_in[15];

  char* ws = (char*)d_ws;
  size_t off = 0;
  auto alloc = [&](size_t bytes){ size_t o = off; off += (bytes + 255) & ~(size_t)255; return o; };
  u16* h_bf   = (u16*)(ws + alloc(4096UL * 1024 * 2));
  u16* Wt_all = (u16*)(ws + alloc(6UL * 1024 * 1024 * 2));
  u16* re_bf  = (u16*)(ws + alloc(512UL * 1024 * 2));
  u16* Qd     = (u16*)(ws + alloc(64UL * 1024 * 64 * 2));
  u16* Kd     = (u16*)(ws + alloc(64UL * 1024 * 64 * 2));
  u16* Vtd    = (u16*)(ws + alloc(64UL * 64 * 1024 * 2));
  u16* posk   = (u16*)(ws + alloc(16UL * 512 * 64 * 2));
  u16* posq   = (u16*)(ws + alloc(16UL * 512 * 64 * 2));
  u16* c2p    = (u16*)(ws + alloc(64UL * 1024 * 512 * 2));
  u16* p2c    = (u16*)(ws + alloc(64UL * 1024 * 512 * 2));
  u16* ctx    = (u16*)(ws + alloc(4096UL * 1024 * 2));
  u16* idxt   = (u16*)(ws + alloc(2048UL * 2));

  u16* Wq_t  = Wt_all;
  u16* Wk_t  = Wt_all + 1048576;
  u16* Wv_t  = Wt_all + 2097152;
  u16* Wo_t  = Wt_all + 3145728;
  u16* Wpk_t = Wt_all + 4194304;
  u16* Wpq_t = Wt_all + 5242880;

  k_conv<<<4096, 256, 0, stream>>>(hs, h_bf, 1048576);
  k_transpose6<<<dim3(16, 16, 6), 256, 0, stream>>>(Wq, Wk, Wv, Wo, Wpk, Wpq, Wt_all);
  k_ln<<<512, 256, 0, stream>>>(rel, lng, lnb, re_bf);
  k_idx<<<8, 256, 0, stream>>>(idxt);

  // projections
  k_gemm<1><<<dim3(8, 32, 1), 256, 0, stream>>>(h_bf, Wq_t, bq, Qd,  4096, 1024, 1024, 1024, 1024, 0, 0, 1, 1);
  k_gemm<1><<<dim3(8, 32, 1), 256, 0, stream>>>(h_bf, Wk_t, bk, Kd,  4096, 1024, 1024, 1024, 1024, 0, 0, 1, 1);
  k_gemm<2><<<dim3(8, 32, 1), 256, 0, stream>>>(h_bf, Wv_t, bv, Vtd, 4096, 1024, 1024, 1024, 1024, 0, 0, 1, 1);
  k_gemm<3><<<dim3(8, 4, 1),  256, 0, stream>>>(re_bf, Wpk_t, bpk, posk, 512, 1024, 1024, 1024, 1024, 0, 0, 1, 1);
  k_gemm<3><<<dim3(8, 4, 1),  256, 0, stream>>>(re_bf, Wpq_t, bpq, posq, 512, 1024, 1024, 1024, 1024, 0, 0, 1, 1);
  // c2p[bh][s][idx] = Q[bh] @ posk[h]^T ; p2c[bh][k][idx] = K[bh] @ posq[h]^T
  k_gemm<4><<<dim3(4, 8, 64), 256, 0, stream>>>(Qd, posk, nullptr, c2p, 1024, 512, 64, 64, 64, 65536, 32768, 64, 16);
  k_gemm<4><<<dim3(4, 8, 64), 256, 0, stream>>>(Kd, posq, nullptr, p2c, 1024, 512, 64, 64, 64, 65536, 32768, 64, 16);

  k_attn<<<dim3(1024), 256, 0, stream>>>(Qd, Kd, Vtd, c2p, p2c, idxt, ctx);

  k_gemm<0><<<dim3(8, 32, 1), 256, 0, stream>>>(ctx, Wo_t, bo, d_out, 4096, 1024, 1024, 1024, 1024, 0, 0, 1, 1);
}

// Round 4
// 354.773 us; speedup vs baseline: 1.4914x; 1.1797x over previous
//
#include <hip/hip_runtime.h>

typedef unsigned short u16;
typedef __attribute__((ext_vector_type(8))) short short8_t;
typedef __attribute__((ext_vector_type(4))) float floatx4;

typedef const void __attribute__((address_space(1)))* gas_ptr;
typedef void __attribute__((address_space(3)))* las_ptr;

__device__ __forceinline__ float bf2f(u16 u){
  union { unsigned i; float f; } v; v.i = ((unsigned)u) << 16; return v.f;
}
__device__ __forceinline__ u16 f2bf(float x){
  unsigned u = __float_as_uint(x);
  return (u16)((u + 0x7FFFu + ((u >> 16) & 1u)) >> 16);
}

// ---------------- fused prep kernel ----------------
// blocks [0,4096): hs f32->bf16          blocks [4096,5632): 6 weight transposes
// blocks [5632,6144): rel_emb LayerNorm  block 6144: idx table + bias concat
__global__ __launch_bounds__(256) void k_prep(
    const float* __restrict__ hs,
    const float* __restrict__ W0, const float* __restrict__ W1, const float* __restrict__ W2,
    const float* __restrict__ W3, const float* __restrict__ W4, const float* __restrict__ W5,
    const float* __restrict__ rel, const float* __restrict__ lng, const float* __restrict__ lnb,
    const float* __restrict__ bq, const float* __restrict__ bk, const float* __restrict__ bv,
    const float* __restrict__ bpk, const float* __restrict__ bpq,
    u16* __restrict__ h_bf, u16* __restrict__ Wt_all, u16* __restrict__ re_bf,
    u16* __restrict__ idxt, float* __restrict__ qkvb, float* __restrict__ posb)
{
  __shared__ float t[64][65];
  const int bid = blockIdx.x, tid = threadIdx.x;
  if (bid < 4096){
    int i = bid * 256 + tid;
    float4 v = ((const float4*)hs)[i];
    ushort4 o;
    o.x = f2bf(v.x); o.y = f2bf(v.y); o.z = f2bf(v.z); o.w = f2bf(v.w);
    ((ushort4*)h_bf)[i] = o;
  } else if (bid < 5632){
    int b2 = bid - 4096;
    int z = b2 >> 8, rem = b2 & 255;
    const float* W = (z == 0) ? W0 : (z == 1) ? W1 : (z == 2) ? W2 : (z == 3) ? W3 : (z == 4) ? W4 : W5;
    u16* Wt = Wt_all + (long)z * 1048576;
    int n0 = (rem & 15) * 64, k0 = (rem >> 4) * 64;
    #pragma unroll
    for (int i = 0; i < 16; i++){
      int e = i * 256 + tid; int r = e >> 6, c = e & 63;
      t[r][c] = W[(long)(k0 + r) * 1024 + n0 + c];
    }
    __syncthreads();
    #pragma unroll
    for (int i = 0; i < 16; i++){
      int e = i * 256 + tid; int r = e >> 6, c = e & 63;
      Wt[(long)(n0 + r) * 1024 + k0 + c] = f2bf(t[c][r]);
    }
  } else if (bid < 6144){
    int row = bid - 5632;
    float* red = (float*)t;
    float4 v = ((const float4*)(rel + (long)row * 1024))[tid];
    float s  = v.x + v.y + v.z + v.w;
    float s2 = v.x*v.x + v.y*v.y + v.z*v.z + v.w*v.w;
    #pragma unroll
    for (int o = 1; o < 64; o <<= 1){ s += __shfl_xor(s, o); s2 += __shfl_xor(s2, o); }
    if ((tid & 63) == 0){ red[(tid >> 6) * 2] = s; red[(tid >> 6) * 2 + 1] = s2; }
    __syncthreads();
    s  = red[0] + red[2] + red[4] + red[6];
    s2 = red[1] + red[3] + red[5] + red[7];
    float mu  = s * (1.f / 1024.f);
    float var = s2 * (1.f / 1024.f) - mu * mu;
    float rs  = rsqrtf(var + 1e-5f);
    float4 gg = ((const float4*)lng)[tid];
    float4 bb = ((const float4*)lnb)[tid];
    ushort4 o;
    o.x = f2bf((v.x - mu) * rs * gg.x + bb.x);
    o.y = f2bf((v.y - mu) * rs * gg.y + bb.y);
    o.z = f2bf((v.z - mu) * rs * gg.z + bb.z);
    o.w = f2bf((v.w - mu) * rs * gg.w + bb.w);
    ((ushort4*)(re_bf + (long)row * 1024))[tid] = o;
  } else {
    for (int i = tid; i < 2047; i += 256){
      int delta = i - 1023;
      int b;
      if (delta >= -128 && delta <= 128) b = delta;
      else {
        float a = (float)(delta < 0 ? -delta : delta);
        float lp = ceilf(logf(a * (1.0f / 128.0f)) / logf(511.0f / 128.0f) * 127.0f) + 128.0f;
        b = (int)lp;
        if (delta < 0) b = -b;
      }
      int idx = b + 256;
      idx = idx < 0 ? 0 : (idx > 511 ? 511 : idx);
      idxt[i] = (u16)idx;
    }
    for (int i = tid; i < 1024; i += 256){
      qkvb[i] = bq[i]; qkvb[1024 + i] = bk[i]; qkvb[2048 + i] = bv[i];
      posb[i] = bpk[i]; posb[1024 + i] = bpq[i];
    }
  }
}

// ---------------- MFMA GEMM: C[M,N] = A[M,K] @ Bt[N,K]^T (+bias) ----------------
// MODE 0: f32 rowmajor ldc=N
// MODE 3: pos GEMM, z in {0,1}: B=Wt+z*1M, bias=posb+z*1024, out u16 [z][h][512][64]
// MODE 4: c2p/p2c batched: z in [0,128): A=Qd+z*65536 (Kd adjacent), B=posk+(z>>6)*524288+(z&15)*32768,
//         C=c2p+z*524288 (p2c adjacent), bf16 rowmajor 1024x512
// MODE 5: fused QKV: N=3072; n<1024 Q layout, n<2048 K layout (Kd=C+4194304), else V^T bounce to C2
template<int MODE>
__global__ __launch_bounds__(256) void k_gemm(
    const u16* __restrict__ A, const u16* __restrict__ Bt,
    const float* __restrict__ bias, void* __restrict__ C, void* __restrict__ C2,
    int M, int N, int K, int lda, int ldb)
{
  __shared__ __attribute__((aligned(16))) u16 smem[16384];   // As 8192 | Bs 8192 elems
  u16* As = smem;
  u16* Bs = smem + 8192;
  const int z = blockIdx.z;
  const u16* Ab = A;
  const u16* Bb = Bt;
  if (MODE == 3){ Bb = Bt + (long)z * 1048576; bias += z << 10; }
  if (MODE == 4){ Ab = A + (long)z * 65536; Bb = Bt + (long)(z >> 6) * 524288 + (long)(z & 15) * 32768; }
  const int m0 = blockIdx.y * 128, n0 = blockIdx.x * 128;
  const int tid = threadIdx.x, lane = tid & 63, w = tid >> 6;
  const int wm = (w >> 1) * 64, wn = (w & 1) * 64;
  floatx4 acc[4][4];
  #pragma unroll
  for (int i = 0; i < 4; i++)
    #pragma unroll
    for (int j = 0; j < 4; j++) acc[i][j] = (floatx4){0.f, 0.f, 0.f, 0.f};

  const int r8 = lane >> 3;
  const int cswz = ((lane & 7) ^ r8) << 4;

  for (int kt = 0; kt < K; kt += 64){
    #pragma unroll
    for (int c = 0; c < 4; c++){
      int row = (c * 4 + w) * 8 + r8;
      const char* ga = (const char*)(Ab + (long)(m0 + row) * lda + kt) + cswz;
      __builtin_amdgcn_global_load_lds((gas_ptr)ga, (las_ptr)((char*)As + (c * 4 + w) * 1024), 16, 0, 0);
      const char* gb = (const char*)(Bb + (long)(n0 + row) * ldb + kt) + cswz;
      __builtin_amdgcn_global_load_lds((gas_ptr)gb, (las_ptr)((char*)Bs + (c * 4 + w) * 1024), 16, 0, 0);
    }
    __syncthreads();
    short8_t af[2][4], bfr[2][4];
    #pragma unroll
    for (int kk = 0; kk < 2; kk++){
      #pragma unroll
      for (int i = 0; i < 4; i++){
        int ra = wm + i * 16 + (lane & 15);
        af[kk][i] = *(const short8_t*)((const char*)As + ra * 128 + ((kk * 64 + ((lane >> 4) << 4)) ^ ((ra & 7) << 4)));
        int rb = wn + i * 16 + (lane & 15);
        bfr[kk][i] = *(const short8_t*)((const char*)Bs + rb * 128 + ((kk * 64 + ((lane >> 4) << 4)) ^ ((rb & 7) << 4)));
      }
    }
    #pragma unroll
    for (int i = 0; i < 4; i++)
      #pragma unroll
      for (int j = 0; j < 4; j++){
        acc[i][j] = __builtin_amdgcn_mfma_f32_16x16x32_bf16(af[0][i], bfr[0][j], acc[i][j], 0, 0, 0);
        acc[i][j] = __builtin_amdgcn_mfma_f32_16x16x32_bf16(af[1][i], bfr[1][j], acc[i][j], 0, 0, 0);
      }
    __syncthreads();
  }

  if (MODE == 5 && n0 >= 2048){
    // V^T via LDS-bounce: write acc transposed (swizzled), stream out coalesced
    #pragma unroll
    for (int i = 0; i < 4; i++){
      #pragma unroll
      for (int j = 0; j < 4; j++){
        #pragma unroll
        for (int r = 0; r < 4; r++){
          int ml = wm + i * 16 + ((lane >> 4) << 2) + r;
          int nl = wn + j * 16 + (lane & 15);
          float v = acc[i][j][r] + bias[n0 + nl];
          int byte_ = nl * 256 + ((ml * 2) ^ ((nl & 7) << 4));
          *(u16*)((char*)smem + byte_) = f2bf(v);
        }
      }
    }
    __syncthreads();
    #pragma unroll
    for (int rr = 0; rr < 8; rr++){
      int nl = rr * 16 + (tid >> 4);
      int np = n0 + nl - 2048;
      int mc = tid & 15;
      short8_t vv = *(const short8_t*)((const char*)smem + nl * 256 + ((mc * 16) ^ ((nl & 7) << 4)));
      int m = m0 + mc * 8;
      long base = ((long)((m >> 10) * 16 + (np >> 6)) * 64 + (np & 63)) * 1024 + (m & 1023);
      *(short8_t*)((u16*)C2 + base) = vv;
    }
    return;
  }

  #pragma unroll
  for (int i = 0; i < 4; i++){
    #pragma unroll
    for (int j = 0; j < 4; j++){
      #pragma unroll
      for (int r = 0; r < 4; r++){
        int m = m0 + wm + i * 16 + ((lane >> 4) << 2) + r;
        int n = n0 + wn + j * 16 + (lane & 15);
        float v = acc[i][j][r] + (bias ? bias[n] : 0.f);
        if (MODE == 0){
          ((float*)C)[(long)m * N + n] = v;
        } else if (MODE == 3){
          ((u16*)C)[(long)z * 524288 + ((long)(n >> 6) * 512 + m) * 64 + (n & 63)] = f2bf(v);
        } else if (MODE == 4){
          ((u16*)C)[(long)z * 524288 + (long)m * 512 + n] = f2bf(v);
        } else if (MODE == 5){
          int mat = n >> 10;       // 0=Q, 1=K
          int np = n & 1023;
          ((u16*)C)[(long)mat * 4194304 +
                    ((long)((m >> 10) * 16 + (np >> 6)) * 1024 + (m & 1023)) * 64 + (np & 63)] = f2bf(v);
        }
      }
    }
  }
}

// ---------------- fused attention (flash-style, no-max softmax) ----------------
// grid 1024 (xcd-chunked -> (bh, sb)), 256 thr = 4 waves, 16 s-rows/wave.
// Q,K [B,H,S,64]; Vt [B,H,64,S]; c2p/p2c [B,H,S,512]; all bf16.
// Phase A gathers c2p s-uniform (coalesced window) into the P-tile; p2c gathered in epilogue.
__global__ __launch_bounds__(256, 4) void k_attn(
    const u16* __restrict__ Q, const u16* __restrict__ K, const u16* __restrict__ Vt,
    const u16* __restrict__ c2p, const u16* __restrict__ p2c,
    const u16* __restrict__ idxt, u16* __restrict__ ctx)
{
  __shared__ __attribute__((aligned(16))) u16 Ks[2][4096];   // [64k][64d] swizzled
  __shared__ __attribute__((aligned(16))) u16 Vs[2][4096];   // [64d][64k] swizzled (V^T)
  __shared__ __attribute__((aligned(16))) u16 Pt[4096];      // [64s][64k] swizzled: bias1 then P
  const int flat0 = blockIdx.x;
  const int flat = (flat0 & 7) * 128 + (flat0 >> 3);   // xcd-chunked
  const int bh = flat >> 4, sb = flat & 15;
  const int tid = threadIdx.x, lane = tid & 63, w = tid >> 6;
  const int s15 = lane & 15, g = lane >> 4;
  const int s0 = sb * 64;
  const int s_row = s0 + w * 16 + s15;
  const u16* Qb  = Q   + (long)bh * 65536;
  const u16* Kg  = K   + (long)bh * 65536;
  const u16* Vg  = Vt  + (long)bh * 65536;
  const u16* c2b = c2p + (long)bh * 524288;
  const u16* p2b = p2c + (long)bh * 524288;

  short8_t qf0 = *(const short8_t*)(Qb + (long)s_row * 64 + g * 8);
  short8_t qf1 = *(const short8_t*)(Qb + (long)s_row * 64 + 32 + g * 8);

  const int srow8  = lane >> 3;
  const int schunk = (lane & 7) ^ (srow8 & 7);
  const float sA = 0.07216878365f;   // 1/sqrt(192)
  const float sB = 0.08838834765f;   // 1/sqrt(128)

  auto STAGE = [&](int buf, int kt){
    #pragma unroll
    for (int ii = 0; ii < 2; ii++){
      int i = w * 2 + ii;
      int row = i * 8 + srow8;
      __builtin_amdgcn_global_load_lds(
        (gas_ptr)((const char*)(Kg + (long)(kt + row) * 64) + schunk * 16),
        (las_ptr)((char*)&Ks[buf][0] + i * 1024), 16, 0, 0);
      __builtin_amdgcn_global_load_lds(
        (gas_ptr)((const char*)(Vg + (long)row * 1024 + kt) + schunk * 16),
        (las_ptr)((char*)&Vs[buf][0] + i * 1024), 16, 0, 0);
    }
  };

  STAGE(0, 0);

  float rowsum = 0.f;
  floatx4 oacc[4];
  #pragma unroll
  for (int dt = 0; dt < 4; dt++) oacc[dt] = (floatx4){0.f, 0.f, 0.f, 0.f};

  const int psw = (s15 & 7) << 4;
  const int myrow = w * 16 + s15;

  for (int t = 0; t < 16; t++){
    const int buf = t & 1;
    const int k0 = t * 64;
    __syncthreads();
    if (t < 15) STAGE(buf ^ 1, k0 + 64);

    // phase A: c2p gather, s-uniform lanes (row s, 64 consecutive k) -> P-tile (bias1)
    #pragma unroll 8
    for (int r = 0; r < 16; r++){
      int sl = w * 16 + r;
      int s  = s0 + sl;
      int dlt = s - (k0 + lane);
      int ix = (int)idxt[dlt + 1023];
      u16 v = c2b[((long)s << 9) + ix];
      *(u16*)((char*)Pt + sl * 128 + (((unsigned)(lane * 2)) ^ ((sl & 7) << 4))) = v;
    }

    // QK^T swapped: a[T] lane holds col s=s15, rows k=g*4+r (k-local T*16+g*4+r)
    floatx4 a[4];
    #pragma unroll
    for (int T = 0; T < 4; T++){
      int row = T * 16 + s15;
      const char* rp = (const char*)&Ks[buf][0] + row * 128;
      int sw = (row & 7) << 4;
      short8_t k0v = *(const short8_t*)(rp + ((g * 16) ^ sw));
      short8_t k1v = *(const short8_t*)(rp + ((64 + g * 16) ^ sw));
      floatx4 acc = (floatx4){0.f, 0.f, 0.f, 0.f};
      acc = __builtin_amdgcn_mfma_f32_16x16x32_bf16(k0v, qf0, acc, 0, 0, 0);
      acc = __builtin_amdgcn_mfma_f32_16x16x32_bf16(k1v, qf1, acc, 0, 0, 0);
      a[T] = acc;
    }

    // epilogue: bias1 from LDS (b64), p2c direct gather, exp, pack P back to same spot
    #pragma unroll
    for (int T = 0; T < 4; T++){
      char* pb = (char*)Pt + myrow * 128 + ((T * 32 + g * 8) ^ psw);
      uint2 b1 = *(uint2*)pb;
      u16 b1v[4] = { (u16)(b1.x & 0xffff), (u16)(b1.x >> 16),
                     (u16)(b1.y & 0xffff), (u16)(b1.y >> 16) };
      int kbase = k0 + T * 16 + g * 4;
      float ev[4];
      #pragma unroll
      for (int e = 0; e < 4; e++){
        int k = kbase + e;
        int ix = (int)idxt[s_row - k + 1023];
        float b2 = bf2f(p2b[((long)k << 9) + ix]);
        ev[e] = __expf(a[T][e] * sA + (bf2f(b1v[e]) + b2) * sB);
      }
      u16 p0 = f2bf(ev[0]), p1 = f2bf(ev[1]), p2v = f2bf(ev[2]), p3 = f2bf(ev[3]);
      rowsum += (bf2f(p0) + bf2f(p1)) + (bf2f(p2v) + bf2f(p3));
      uint2 pk2;
      pk2.x = (unsigned)p0  | ((unsigned)p1 << 16);
      pk2.y = (unsigned)p2v | ((unsigned)p3 << 16);
      *(uint2*)pb = pk2;
    }

    // PV: O[s,d] += P[s,:] V[:,d]  (P rows wave-private)
    #pragma unroll
    for (int M = 0; M < 2; M++){
      short8_t pf = *(const short8_t*)((const char*)Pt + myrow * 128 + ((M * 64 + g * 16) ^ psw));
      #pragma unroll
      for (int dt = 0; dt < 4; dt++){
        int drow = dt * 16 + s15;
        short8_t vf = *(const short8_t*)((const char*)&Vs[buf][0] + drow * 128 + ((M * 64 + g * 16) ^ ((drow & 7) << 4)));
        oacc[dt] = __builtin_amdgcn_mfma_f32_16x16x32_bf16(pf, vf, oacc[dt], 0, 0, 0);
      }
    }
  }

  rowsum += __shfl_xor(rowsum, 16);
  rowsum += __shfl_xor(rowsum, 32);
  float rinv = 1.f / rowsum;

  const int b = bh >> 4, h = bh & 15;
  #pragma unroll
  for (int r = 0; r < 4; r++){
    float ri = __shfl(rinv, g * 4 + r);
    int s_out = s0 + w * 16 + g * 4 + r;
    #pragma unroll
    for (int dt = 0; dt < 4; dt++){
      long oi = ((long)b * 1024 + s_out) * 1024 + h * 64 + dt * 16 + s15;
      ctx[oi] = f2bf(oacc[dt][r] * ri);
    }
  }
}

// ---------------- launch ----------------
extern "C" void kernel_launch(void* const* d_in, const int* in_sizes, int n_in,
                              void* d_out, int out_size, void* d_ws, size_t ws_size,
                              hipStream_t stream){
  const float* hs  = (const float*)d_in[0];
  const float* Wq  = (const float*)d_in[1];
  const float* bq  = (const float*)d_in[2];
  const float* Wk  = (const float*)d_in[3];
  const float* bk  = (const float*)d_in[4];
  const float* Wv  = (const float*)d_in[5];
  const float* bv  = (const float*)d_in[6];
  const float* Wo  = (const float*)d_in[7];
  const float* bo  = (const float*)d_in[8];
  const float* rel = (const float*)d_in[9];
  const float* lng = (const float*)d_in[10];
  const float* lnb = (const float*)d_in[11];
  const float* Wpk = (const float*)d_in[12];
  const float* bpk = (const float*)d_in[13];
  const float* Wpq = (const float*)d_in[14];
  const float* bpq = (const float*)d_in[15];

  char* ws = (char*)d_ws;
  size_t off = 0;
  auto alloc = [&](size_t bytes){ size_t o = off; off += (bytes + 255) & ~(size_t)255; return o; };
  u16* h_bf   = (u16*)(ws + alloc(4194304UL * 2));   // [4096,1024] bf16
  u16* Wt_all = (u16*)(ws + alloc(6291456UL * 2));   // 6x [1024,1024] transposed
  u16* re_bf  = (u16*)(ws + alloc(524288UL * 2));    // [512,1024]
  u16* Qd     = (u16*)(ws + alloc(4194304UL * 2));   // [64bh,1024,64]
  u16* Kd     = (u16*)(ws + alloc(4194304UL * 2));   // adjacent to Qd
  u16* Vtd    = (u16*)(ws + alloc(4194304UL * 2));   // [64bh,64,1024]
  u16* posk   = (u16*)(ws + alloc(524288UL * 2));    // [16h,512,64]
  u16* posq   = (u16*)(ws + alloc(524288UL * 2));    // adjacent to posk
  u16* c2p    = (u16*)(ws + alloc(33554432UL * 2));  // [64bh,1024,512]
  u16* p2c    = (u16*)(ws + alloc(33554432UL * 2));  // adjacent to c2p
  u16* ctx    = (u16*)(ws + alloc(4194304UL * 2));
  u16* idxt   = (u16*)(ws + alloc(2048UL * 2));
  float* qkvb = (float*)(ws + alloc(3072UL * 4));
  float* posb = (float*)(ws + alloc(2048UL * 4));
  (void)posq; (void)p2c; (void)Kd;

  k_prep<<<6145, 256, 0, stream>>>(hs, Wq, Wk, Wv, Wo, Wpk, Wpq, rel, lng, lnb,
                                   bq, bk, bv, bpk, bpq,
                                   h_bf, Wt_all, re_bf, idxt, qkvb, posb);

  // fused QKV projection: N=3072 (Wq|Wk|Wv transposed are contiguous in Wt_all)
  k_gemm<5><<<dim3(24, 32, 1), 256, 0, stream>>>(h_bf, Wt_all, qkvb, Qd, Vtd,
                                                 4096, 3072, 1024, 1024, 1024);
  // posk / posq (z=0/1)
  k_gemm<3><<<dim3(8, 4, 2), 256, 0, stream>>>(re_bf, Wt_all + 4194304, posb, posk, nullptr,
                                               512, 1024, 1024, 1024, 1024);
  // c2p (z<64) / p2c (z>=64), batched over bh
  k_gemm<4><<<dim3(4, 8, 128), 256, 0, stream>>>(Qd, posk, nullptr, c2p, nullptr,
                                                 1024, 512, 64, 64, 64);

  k_attn<<<dim3(1024), 256, 0, stream>>>(Qd, Kd, Vtd, c2p, p2c, idxt, ctx);

  // output projection (f32 out)
  k_gemm<0><<<dim3(8, 32, 1), 256, 0, stream>>>(ctx, Wt_all + 3145728, bo, d_out, nullptr,
                                                4096, 1024, 1024, 1024, 1024);
}

// Round 5
// 307.913 us; speedup vs baseline: 1.7184x; 1.1522x over previous
//
#include <hip/hip_runtime.h>

typedef unsigned short u16;
typedef __attribute__((ext_vector_type(8))) short short8_t;
typedef __attribute__((ext_vector_type(4))) float floatx4;

typedef const void __attribute__((address_space(1)))* gas_ptr;
typedef void __attribute__((address_space(3)))* las_ptr;

__device__ __forceinline__ float bf2f(u16 u){
  union { unsigned i; float f; } v; v.i = ((unsigned)u) << 16; return v.f;
}
__device__ __forceinline__ u16 f2bf(float x){
  unsigned u = __float_as_uint(x);
  return (u16)((u + 0x7FFFu + ((u >> 16) & 1u)) >> 16);
}
__device__ __forceinline__ int bucket_idx(int delta){
  int b;
  if (delta >= -128 && delta <= 128) b = delta;
  else {
    float a = (float)(delta < 0 ? -delta : delta);
    float lp = ceilf(logf(a * (1.0f / 128.0f)) / logf(511.0f / 128.0f) * 127.0f) + 128.0f;
    b = (int)lp;
    if (delta < 0) b = -b;
  }
  int idx = b + 256;
  return idx < 0 ? 0 : (idx > 511 ? 511 : idx);
}

// ---------------- fused prep kernel ----------------
// blocks [0,4096): hs f32->bf16          blocks [4096,5632): 6 weight transposes
// blocks [5632,6144): rel_emb LayerNorm  block 6144: tables + bias concat
__global__ __launch_bounds__(256) void k_prep(
    const float* __restrict__ hs,
    const float* __restrict__ W0, const float* __restrict__ W1, const float* __restrict__ W2,
    const float* __restrict__ W3, const float* __restrict__ W4, const float* __restrict__ W5,
    const float* __restrict__ rel, const float* __restrict__ lng, const float* __restrict__ lnb,
    const float* __restrict__ bq, const float* __restrict__ bk, const float* __restrict__ bv,
    const float* __restrict__ bpk, const float* __restrict__ bpq,
    u16* __restrict__ h_bf, u16* __restrict__ Wt_all, u16* __restrict__ re_bf,
    u16* __restrict__ idxt, u16* __restrict__ ixlo_tbl,
    float* __restrict__ qkvb, float* __restrict__ posb)
{
  __shared__ float t[64][65];
  const int bid = blockIdx.x, tid = threadIdx.x;
  if (bid < 4096){
    int i = bid * 256 + tid;
    float4 v = ((const float4*)hs)[i];
    ushort4 o;
    o.x = f2bf(v.x); o.y = f2bf(v.y); o.z = f2bf(v.z); o.w = f2bf(v.w);
    ((ushort4*)h_bf)[i] = o;
  } else if (bid < 5632){
    int b2 = bid - 4096;
    int z = b2 >> 8, rem = b2 & 255;
    const float* W = (z == 0) ? W0 : (z == 1) ? W1 : (z == 2) ? W2 : (z == 3) ? W3 : (z == 4) ? W4 : W5;
    u16* Wt = Wt_all + (long)z * 1048576;
    int n0 = (rem & 15) * 64, k0 = (rem >> 4) * 64;
    #pragma unroll
    for (int i = 0; i < 16; i++){
      int e = i * 256 + tid; int r = e >> 6, c = e & 63;
      t[r][c] = W[(long)(k0 + r) * 1024 + n0 + c];
    }
    __syncthreads();
    #pragma unroll
    for (int i = 0; i < 16; i++){
      int e = i * 256 + tid; int r = e >> 6, c = e & 63;
      Wt[(long)(n0 + r) * 1024 + k0 + c] = f2bf(t[c][r]);
    }
  } else if (bid < 6144){
    int row = bid - 5632;
    float* red = (float*)t;
    float4 v = ((const float4*)(rel + (long)row * 1024))[tid];
    float s  = v.x + v.y + v.z + v.w;
    float s2 = v.x*v.x + v.y*v.y + v.z*v.z + v.w*v.w;
    #pragma unroll
    for (int o = 1; o < 64; o <<= 1){ s += __shfl_xor(s, o); s2 += __shfl_xor(s2, o); }
    if ((tid & 63) == 0){ red[(tid >> 6) * 2] = s; red[(tid >> 6) * 2 + 1] = s2; }
    __syncthreads();
    s  = red[0] + red[2] + red[4] + red[6];
    s2 = red[1] + red[3] + red[5] + red[7];
    float mu  = s * (1.f / 1024.f);
    float var = s2 * (1.f / 1024.f) - mu * mu;
    float rs  = rsqrtf(var + 1e-5f);
    float4 gg = ((const float4*)lng)[tid];
    float4 bb = ((const float4*)lnb)[tid];
    ushort4 o;
    o.x = f2bf((v.x - mu) * rs * gg.x + bb.x);
    o.y = f2bf((v.y - mu) * rs * gg.y + bb.y);
    o.z = f2bf((v.z - mu) * rs * gg.z + bb.z);
    o.w = f2bf((v.w - mu) * rs * gg.w + bb.w);
    ((ushort4*)(re_bf + (long)row * 1024))[tid] = o;
  } else {
    // idx table rebased: idxt[i] = bucket(i - 1024), i in [0,2048)
    for (int i = tid; i < 2048; i += 256)
      idxt[i] = (u16)bucket_idx(i - 1024);
    // per-(sb,t) window starts
    if (tid < 256){
      int sb = tid >> 4, tt = tid & 15;
      int dlo = sb * 64 - tt * 64 - 63;
      int lo = bucket_idx(dlo) & ~1;
      if (lo > 384) lo = 384;
      ixlo_tbl[tid] = (u16)lo;
    }
    for (int i = tid; i < 1024; i += 256){
      qkvb[i] = bq[i]; qkvb[1024 + i] = bk[i]; qkvb[2048 + i] = bv[i];
      posb[i] = bpk[i]; posb[1024 + i] = bpq[i];
    }
  }
}

// ---------------- MFMA GEMM: C[M,N] = A[M,K] @ Bt[N,K]^T (+bias) ----------------
// MODE 0: f32 rowmajor ldc=N
// MODE 3: pos GEMM, z in {0,1}: B=Wt+z*1M, bias=posb+z*1024, out u16 [z][h][512][64]
// MODE 4: c2p/p2c batched: z in [0,128)
// MODE 5: fused QKV: N=3072; n<1024 Q layout, n<2048 K layout, else V^T bounce to C2
template<int MODE>
__global__ __launch_bounds__(256) void k_gemm(
    const u16* __restrict__ A, const u16* __restrict__ Bt,
    const float* __restrict__ bias, void* __restrict__ C, void* __restrict__ C2,
    int M, int N, int K, int lda, int ldb)
{
  __shared__ __attribute__((aligned(16))) u16 smem[16384];   // As 8192 | Bs 8192 elems
  u16* As = smem;
  u16* Bs = smem + 8192;
  const int z = blockIdx.z;
  const u16* Ab = A;
  const u16* Bb = Bt;
  if (MODE == 3){ Bb = Bt + (long)z * 1048576; bias += z << 10; }
  if (MODE == 4){ Ab = A + (long)z * 65536; Bb = Bt + (long)(z >> 6) * 524288 + (long)(z & 15) * 32768; }
  const int m0 = blockIdx.y * 128, n0 = blockIdx.x * 128;
  const int tid = threadIdx.x, lane = tid & 63, w = tid >> 6;
  const int wm = (w >> 1) * 64, wn = (w & 1) * 64;
  floatx4 acc[4][4];
  #pragma unroll
  for (int i = 0; i < 4; i++)
    #pragma unroll
    for (int j = 0; j < 4; j++) acc[i][j] = (floatx4){0.f, 0.f, 0.f, 0.f};

  const int r8 = lane >> 3;
  const int cswz = ((lane & 7) ^ r8) << 4;

  for (int kt = 0; kt < K; kt += 64){
    #pragma unroll
    for (int c = 0; c < 4; c++){
      int row = (c * 4 + w) * 8 + r8;
      const char* ga = (const char*)(Ab + (long)(m0 + row) * lda + kt) + cswz;
      __builtin_amdgcn_global_load_lds((gas_ptr)ga, (las_ptr)((char*)As + (c * 4 + w) * 1024), 16, 0, 0);
      const char* gb = (const char*)(Bb + (long)(n0 + row) * ldb + kt) + cswz;
      __builtin_amdgcn_global_load_lds((gas_ptr)gb, (las_ptr)((char*)Bs + (c * 4 + w) * 1024), 16, 0, 0);
    }
    __syncthreads();
    short8_t af[2][4], bfr[2][4];
    #pragma unroll
    for (int kk = 0; kk < 2; kk++){
      #pragma unroll
      for (int i = 0; i < 4; i++){
        int ra = wm + i * 16 + (lane & 15);
        af[kk][i] = *(const short8_t*)((const char*)As + ra * 128 + ((kk * 64 + ((lane >> 4) << 4)) ^ ((ra & 7) << 4)));
        int rb = wn + i * 16 + (lane & 15);
        bfr[kk][i] = *(const short8_t*)((const char*)Bs + rb * 128 + ((kk * 64 + ((lane >> 4) << 4)) ^ ((rb & 7) << 4)));
      }
    }
    #pragma unroll
    for (int i = 0; i < 4; i++)
      #pragma unroll
      for (int j = 0; j < 4; j++){
        acc[i][j] = __builtin_amdgcn_mfma_f32_16x16x32_bf16(af[0][i], bfr[0][j], acc[i][j], 0, 0, 0);
        acc[i][j] = __builtin_amdgcn_mfma_f32_16x16x32_bf16(af[1][i], bfr[1][j], acc[i][j], 0, 0, 0);
      }
    __syncthreads();
  }

  if (MODE == 5 && n0 >= 2048){
    #pragma unroll
    for (int i = 0; i < 4; i++){
      #pragma unroll
      for (int j = 0; j < 4; j++){
        #pragma unroll
        for (int r = 0; r < 4; r++){
          int ml = wm + i * 16 + ((lane >> 4) << 2) + r;
          int nl = wn + j * 16 + (lane & 15);
          float v = acc[i][j][r] + bias[n0 + nl];
          int byte_ = nl * 256 + ((ml * 2) ^ ((nl & 7) << 4));
          *(u16*)((char*)smem + byte_) = f2bf(v);
        }
      }
    }
    __syncthreads();
    #pragma unroll
    for (int rr = 0; rr < 8; rr++){
      int nl = rr * 16 + (tid >> 4);
      int np = n0 + nl - 2048;
      int mc = tid & 15;
      short8_t vv = *(const short8_t*)((const char*)smem + nl * 256 + ((mc * 16) ^ ((nl & 7) << 4)));
      int m = m0 + mc * 8;
      long base = ((long)((m >> 10) * 16 + (np >> 6)) * 64 + (np & 63)) * 1024 + (m & 1023);
      *(short8_t*)((u16*)C2 + base) = vv;
    }
    return;
  }

  #pragma unroll
  for (int i = 0; i < 4; i++){
    #pragma unroll
    for (int j = 0; j < 4; j++){
      #pragma unroll
      for (int r = 0; r < 4; r++){
        int m = m0 + wm + i * 16 + ((lane >> 4) << 2) + r;
        int n = n0 + wn + j * 16 + (lane & 15);
        float v = acc[i][j][r] + (bias ? bias[n] : 0.f);
        if (MODE == 0){
          ((float*)C)[(long)m * N + n] = v;
        } else if (MODE == 3){
          ((u16*)C)[(long)z * 524288 + ((long)(n >> 6) * 512 + m) * 64 + (n & 63)] = f2bf(v);
        } else if (MODE == 4){
          ((u16*)C)[(long)z * 524288 + (long)m * 512 + n] = f2bf(v);
        } else if (MODE == 5){
          int mat = n >> 10;
          int np = n & 1023;
          ((u16*)C)[(long)mat * 4194304 +
                    ((long)((m >> 10) * 16 + (np >> 6)) * 1024 + (m & 1023)) * 64 + (np & 63)] = f2bf(v);
        }
      }
    }
  }
}

// ---------------- fused attention (flash-style, window-staged bias) ----------------
// grid 1024 (xcd-chunked -> (bh, sb)), 256 thr = 4 waves, 16 s-rows/wave.
// All bias gathers are LDS-local: per-tile contiguous windows of c2p/p2c/idxt are
// prefetched with width-4 global_load_lds (XOR-preswizzled source).
__global__ __launch_bounds__(256, 2) void k_attn(
    const u16* __restrict__ Q, const u16* __restrict__ K, const u16* __restrict__ Vt,
    const u16* __restrict__ c2p, const u16* __restrict__ p2c,
    const u16* __restrict__ T3, const u16* __restrict__ ixlo_tbl,
    u16* __restrict__ ctx)
{
  __shared__ __attribute__((aligned(16))) u16 Ks[2][4096];   // [64k][64d] swizzled
  __shared__ __attribute__((aligned(16))) u16 Vs[2][4096];   // [64d][64k] swizzled (V^T)
  __shared__ __attribute__((aligned(16))) u16 Pt[4096];      // [64s][64k] swizzled
  __shared__ __attribute__((aligned(16))) u16 C2W[8192];     // [64s][128] window, key=row&15
  __shared__ __attribute__((aligned(16))) u16 P2W[8192];     // [64k][128] window, key=row&15
  __shared__ __attribute__((aligned(16))) u16 IDW[4][128];   // per-wave idx window
  const int flat0 = blockIdx.x;
  const int flat = (flat0 & 7) * 128 + (flat0 >> 3);   // xcd-chunked
  const int bh = flat >> 4, sb = flat & 15;
  const int tid = threadIdx.x, lane = tid & 63, w = tid >> 6;
  const int s15 = lane & 15, g = lane >> 4;
  const int s0 = sb * 64;
  const int myrow = w * 16 + s15;
  const int s_row = s0 + myrow;
  const u16* Qb  = Q   + (long)bh * 65536;
  const u16* Kg  = K   + (long)bh * 65536;
  const u16* Vg  = Vt  + (long)bh * 65536;
  const u16* c2b = c2p + (long)bh * 524288;
  const u16* p2b = p2c + (long)bh * 524288;

  short8_t qf0 = *(const short8_t*)(Qb + (long)s_row * 64 + g * 8);
  short8_t qf1 = *(const short8_t*)(Qb + (long)s_row * 64 + 32 + g * 8);

  const int srow8  = lane >> 3;
  const int schunk = (lane & 7) ^ srow8;
  const float sA2 = 0.10411754f;   // 1/sqrt(192) * log2(e)
  const float sB2 = 0.12751743f;   // 1/sqrt(128) * log2(e)
  const int wswz = (lane * 4) & 63;          // lane byte within 64
  const int wkey = ((lane * 4) ^ 0);         // placeholder (unused)

  auto STAGEKV = [&](int buf, int kt){
    #pragma unroll
    for (int ii = 0; ii < 2; ii++){
      int i = w * 2 + ii;
      int row = i * 8 + srow8;
      __builtin_amdgcn_global_load_lds(
        (gas_ptr)((const char*)(Kg + (long)(kt + row) * 64) + schunk * 16),
        (las_ptr)((char*)&Ks[buf][0] + i * 1024), 16, 0, 0);
      __builtin_amdgcn_global_load_lds(
        (gas_ptr)((const char*)(Vg + (long)row * 1024 + kt) + schunk * 16),
        (las_ptr)((char*)&Vs[buf][0] + i * 1024), 16, 0, 0);
    }
  };
  // stage one 256B window row with XOR-preswizzled source (key = row&15)
  auto STAGEROW = [&](const u16* rowptr, u16* ldsbase, int row){
    const char* src = (const char*)rowptr + (((lane * 4) ^ ((row & 15) << 4)));
    __builtin_amdgcn_global_load_lds((gas_ptr)src, (las_ptr)((char*)ldsbase + row * 256), 4, 0, 0);
  };

  const int tb16 = sb * 16;
  int ixlo_cur = (int)ixlo_tbl[tb16];

  // prologue: stage p2w(0), idw(0), K/V(0)
  #pragma unroll
  for (int r = 0; r < 16; r++){
    int row = w * 16 + r;
    STAGEROW(p2b + (long)row * 512 + ixlo_cur, P2W, row);
  }
  {
    int dev = s0 - 64;
    __builtin_amdgcn_global_load_lds((gas_ptr)((const char*)(T3 + (dev + 1024)) + lane * 4),
                                     (las_ptr)((char*)IDW + w * 256), 4, 0, 0);
  }
  STAGEKV(0, 0);

  float rowsum = 0.f;
  floatx4 oacc[4];
  #pragma unroll
  for (int dt = 0; dt < 4; dt++) oacc[dt] = (floatx4){0.f, 0.f, 0.f, 0.f};

  const int psw = (myrow & 7) << 4;
  const int c2wkey = (myrow & 15) << 4;

  __syncthreads();   // barrier A for t=0

  for (int t = 0; t < 16; t++){
    const int buf = t & 1;
    const int k0 = t * 64;

    int ixlo_next = 0;
    if (t < 15) ixlo_next = (int)ixlo_tbl[tb16 + t + 1];
    if (t < 15) STAGEKV(buf ^ 1, k0 + 64);
    // c2w(t): wave-private rows, consumed by this wave after vmcnt drain
    #pragma unroll
    for (int r = 0; r < 16; r++){
      int row = w * 16 + r;
      STAGEROW(c2b + (long)(s0 + row) * 512 + ixlo_cur, C2W, row);
    }

    // QK^T swapped: a[T] lane holds col s=s15, rows k (T*16+g*4+e)
    floatx4 a[4];
    #pragma unroll
    for (int T = 0; T < 4; T++){
      int row = T * 16 + s15;
      const char* rp = (const char*)&Ks[buf][0] + row * 128;
      int sw = (row & 7) << 4;
      short8_t k0v = *(const short8_t*)(rp + ((g * 16) ^ sw));
      short8_t k1v = *(const short8_t*)(rp + ((64 + g * 16) ^ sw));
      floatx4 acc = (floatx4){0.f, 0.f, 0.f, 0.f};
      acc = __builtin_amdgcn_mfma_f32_16x16x32_bf16(k0v, qf0, acc, 0, 0, 0);
      acc = __builtin_amdgcn_mfma_f32_16x16x32_bf16(k1v, qf1, acc, 0, 0, 0);
      a[T] = acc;
    }

    asm volatile("s_waitcnt vmcnt(0)" ::: "memory");   // c2w/idw/KV landed

    // epilogue: all gathers LDS-local
    #pragma unroll
    for (int T = 0; T < 4; T++){
      int klb = T * 16 + g * 4;
      int jb = myrow + 64 - klb;        // idw index for e: jb - e, in [1,127]
      u16 pv[4];
      #pragma unroll
      for (int e = 0; e < 4; e++){
        int ix = (int)*(const u16*)((const char*)IDW + w * 256 + (jb - e) * 2);
        int x = (ix - ixlo_cur) * 2;
        int kl = klb + e;
        u16 b1 = *(const u16*)((const char*)C2W + myrow * 256 + (x ^ c2wkey));
        u16 b2 = *(const u16*)((const char*)P2W + kl * 256 + (x ^ ((kl & 15) << 4)));
        float bs = bf2f(b1) + bf2f(b2);
        float ev = exp2f(a[T][e] * sA2 + bs * sB2);
        pv[e] = f2bf(ev);
        rowsum += bf2f(pv[e]);
      }
      uint2 pk2;
      pk2.x = (unsigned)pv[0] | ((unsigned)pv[1] << 16);
      pk2.y = (unsigned)pv[2] | ((unsigned)pv[3] << 16);
      *(uint2*)((char*)Pt + myrow * 128 + ((T * 32 + g * 8) ^ psw)) = pk2;
    }

    __syncthreads();   // barrier B: all waves done reading P2W(t)/IDW(t)

    if (t < 15){
      // p2w(t+1) + idw(t+1): latency hidden under PV
      #pragma unroll
      for (int r = 0; r < 16; r++){
        int row = w * 16 + r;
        STAGEROW(p2b + (long)(k0 + 64 + row) * 512 + ixlo_next, P2W, row);
      }
      int dev = s0 - (k0 + 64) - 64;
      __builtin_amdgcn_global_load_lds((gas_ptr)((const char*)(T3 + (dev + 1024)) + lane * 4),
                                       (las_ptr)((char*)IDW + w * 256), 4, 0, 0);
    }

    // PV: O[s,d] += P[s,:] V[:,d]
    #pragma unroll
    for (int M = 0; M < 2; M++){
      short8_t pf = *(const short8_t*)((const char*)Pt + myrow * 128 + ((M * 64 + g * 16) ^ psw));
      #pragma unroll
      for (int dt = 0; dt < 4; dt++){
        int drow = dt * 16 + s15;
        short8_t vf = *(const short8_t*)((const char*)&Vs[buf][0] + drow * 128 + ((M * 64 + g * 16) ^ ((drow & 7) << 4)));
        oacc[dt] = __builtin_amdgcn_mfma_f32_16x16x32_bf16(pf, vf, oacc[dt], 0, 0, 0);
      }
    }

    ixlo_cur = ixlo_next;
    __syncthreads();   // barrier A for t+1 (drains p2w/idw staging)
  }

  rowsum += __shfl_xor(rowsum, 16);
  rowsum += __shfl_xor(rowsum, 32);
  float rinv = 1.f / rowsum;

  const int b = bh >> 4, h = bh & 15;
  #pragma unroll
  for (int r = 0; r < 4; r++){
    float ri = __shfl(rinv, g * 4 + r);
    int s_out = s0 + w * 16 + g * 4 + r;
    #pragma unroll
    for (int dt = 0; dt < 4; dt++){
      long oi = ((long)b * 1024 + s_out) * 1024 + h * 64 + dt * 16 + s15;
      ctx[oi] = f2bf(oacc[dt][r] * ri);
    }
  }
}

// ---------------- launch ----------------
extern "C" void kernel_launch(void* const* d_in, const int* in_sizes, int n_in,
                              void* d_out, int out_size, void* d_ws, size_t ws_size,
                              hipStream_t stream){
  const float* hs  = (const float*)d_in[0];
  const float* Wq  = (const float*)d_in[1];
  const float* bq  = (const float*)d_in[2];
  const float* Wk  = (const float*)d_in[3];
  const float* bk  = (const float*)d_in[4];
  const float* Wv  = (const float*)d_in[5];
  const float* bv  = (const float*)d_in[6];
  const float* Wo  = (const float*)d_in[7];
  const float* bo  = (const float*)d_in[8];
  const float* rel = (const float*)d_in[9];
  const float* lng = (const float*)d_in[10];
  const float* lnb = (const float*)d_in[11];
  const float* Wpk = (const float*)d_in[12];
  const float* bpk = (const float*)d_in[13];
  const float* Wpq = (const float*)d_in[14];
  const float* bpq = (const float*)d_in[15];

  char* ws = (char*)d_ws;
  size_t off = 0;
  auto alloc = [&](size_t bytes){ size_t o = off; off += (bytes + 255) & ~(size_t)255; return o; };
  u16* h_bf   = (u16*)(ws + alloc(4194304UL * 2));   // [4096,1024] bf16
  u16* Wt_all = (u16*)(ws + alloc(6291456UL * 2));   // 6x [1024,1024] transposed
  u16* re_bf  = (u16*)(ws + alloc(524288UL * 2));    // [512,1024]
  u16* Qd     = (u16*)(ws + alloc(4194304UL * 2));   // [64bh,1024,64]
  u16* Kd     = (u16*)(ws + alloc(4194304UL * 2));   // adjacent to Qd
  u16* Vtd    = (u16*)(ws + alloc(4194304UL * 2));   // [64bh,64,1024]
  u16* posk   = (u16*)(ws + alloc(524288UL * 2));    // [16h,512,64]
  u16* posq   = (u16*)(ws + alloc(524288UL * 2));    // adjacent to posk
  u16* c2p    = (u16*)(ws + alloc(33554432UL * 2));  // [64bh,1024,512]
  u16* p2c    = (u16*)(ws + alloc(33554432UL * 2));  // adjacent to c2p
  u16* ctx    = (u16*)(ws + alloc(4194304UL * 2));
  u16* idxt   = (u16*)(ws + alloc(2048UL * 2));      // bucket(i-1024)
  u16* ixlo   = (u16*)(ws + alloc(256UL * 2));       // per (sb,t) window start
  float* qkvb = (float*)(ws + alloc(3072UL * 4));
  float* posb = (float*)(ws + alloc(2048UL * 4));
  (void)posq; (void)p2c; (void)Kd;

  k_prep<<<6145, 256, 0, stream>>>(hs, Wq, Wk, Wv, Wo, Wpk, Wpq, rel, lng, lnb,
                                   bq, bk, bv, bpk, bpq,
                                   h_bf, Wt_all, re_bf, idxt, ixlo, qkvb, posb);

  // fused QKV projection: N=3072 (Wq|Wk|Wv transposed contiguous in Wt_all)
  k_gemm<5><<<dim3(24, 32, 1), 256, 0, stream>>>(h_bf, Wt_all, qkvb, Qd, Vtd,
                                                 4096, 3072, 1024, 1024, 1024);
  // posk / posq (z=0/1)
  k_gemm<3><<<dim3(8, 4, 2), 256, 0, stream>>>(re_bf, Wt_all + 4194304, posb, posk, nullptr,
                                               512, 1024, 1024, 1024, 1024);
  // c2p (z<64) / p2c (z>=64), batched over bh
  k_gemm<4><<<dim3(4, 8, 128), 256, 0, stream>>>(Qd, posk, nullptr, c2p, nullptr,
                                                 1024, 512, 64, 64, 64);

  k_attn<<<dim3(1024), 256, 0, stream>>>(Qd, Kd, Vtd, c2p, p2c, idxt, ixlo, ctx);

  // output projection (f32 out)
  k_gemm<0><<<dim3(8, 32, 1), 256, 0, stream>>>(ctx, Wt_all + 3145728, bo, d_out, nullptr,
                                                4096, 1024, 1024, 1024, 1024);
}

// Round 6
// 306.673 us; speedup vs baseline: 1.7253x; 1.0040x over previous
//
#include <hip/hip_runtime.h>

typedef unsigned short u16;
typedef __attribute__((ext_vector_type(8))) short short8_t;
typedef __attribute__((ext_vector_type(4))) float floatx4;

typedef const void __attribute__((address_space(1)))* gas_ptr;
typedef void __attribute__((address_space(3)))* las_ptr;

__device__ __forceinline__ float bf2f(u16 u){
  union { unsigned i; float f; } v; v.i = ((unsigned)u) << 16; return v.f;
}
__device__ __forceinline__ u16 f2bf(float x){
  unsigned u = __float_as_uint(x);
  return (u16)((u + 0x7FFFu + ((u >> 16) & 1u)) >> 16);
}
__device__ __forceinline__ int bucket_idx(int delta){
  int b;
  if (delta >= -128 && delta <= 128) b = delta;
  else {
    float a = (float)(delta < 0 ? -delta : delta);
    float lp = ceilf(logf(a * (1.0f / 128.0f)) / logf(511.0f / 128.0f) * 127.0f) + 128.0f;
    b = (int)lp;
    if (delta < 0) b = -b;
  }
  int idx = b + 256;
  return idx < 0 ? 0 : (idx > 511 ? 511 : idx);
}

// ---------------- fused prep kernel ----------------
__global__ __launch_bounds__(256) void k_prep(
    const float* __restrict__ hs,
    const float* __restrict__ W0, const float* __restrict__ W1, const float* __restrict__ W2,
    const float* __restrict__ W3, const float* __restrict__ W4, const float* __restrict__ W5,
    const float* __restrict__ rel, const float* __restrict__ lng, const float* __restrict__ lnb,
    const float* __restrict__ bq, const float* __restrict__ bk, const float* __restrict__ bv,
    const float* __restrict__ bpk, const float* __restrict__ bpq,
    u16* __restrict__ h_bf, u16* __restrict__ Wt_all, u16* __restrict__ re_bf,
    u16* __restrict__ idxt, u16* __restrict__ ixlo_tbl,
    float* __restrict__ qkvb, float* __restrict__ posb)
{
  __shared__ float t[64][65];
  const int bid = blockIdx.x, tid = threadIdx.x;
  if (bid < 4096){
    int i = bid * 256 + tid;
    float4 v = ((const float4*)hs)[i];
    ushort4 o;
    o.x = f2bf(v.x); o.y = f2bf(v.y); o.z = f2bf(v.z); o.w = f2bf(v.w);
    ((ushort4*)h_bf)[i] = o;
  } else if (bid < 5632){
    int b2 = bid - 4096;
    int z = b2 >> 8, rem = b2 & 255;
    const float* W = (z == 0) ? W0 : (z == 1) ? W1 : (z == 2) ? W2 : (z == 3) ? W3 : (z == 4) ? W4 : W5;
    u16* Wt = Wt_all + (long)z * 1048576;
    int n0 = (rem & 15) * 64, k0 = (rem >> 4) * 64;
    #pragma unroll
    for (int i = 0; i < 16; i++){
      int e = i * 256 + tid; int r = e >> 6, c = e & 63;
      t[r][c] = W[(long)(k0 + r) * 1024 + n0 + c];
    }
    __syncthreads();
    #pragma unroll
    for (int i = 0; i < 16; i++){
      int e = i * 256 + tid; int r = e >> 6, c = e & 63;
      Wt[(long)(n0 + r) * 1024 + k0 + c] = f2bf(t[c][r]);
    }
  } else if (bid < 6144){
    int row = bid - 5632;
    float* red = (float*)t;
    float4 v = ((const float4*)(rel + (long)row * 1024))[tid];
    float s  = v.x + v.y + v.z + v.w;
    float s2 = v.x*v.x + v.y*v.y + v.z*v.z + v.w*v.w;
    #pragma unroll
    for (int o = 1; o < 64; o <<= 1){ s += __shfl_xor(s, o); s2 += __shfl_xor(s2, o); }
    if ((tid & 63) == 0){ red[(tid >> 6) * 2] = s; red[(tid >> 6) * 2 + 1] = s2; }
    __syncthreads();
    s  = red[0] + red[2] + red[4] + red[6];
    s2 = red[1] + red[3] + red[5] + red[7];
    float mu  = s * (1.f / 1024.f);
    float var = s2 * (1.f / 1024.f) - mu * mu;
    float rs  = rsqrtf(var + 1e-5f);
    float4 gg = ((const float4*)lng)[tid];
    float4 bb = ((const float4*)lnb)[tid];
    ushort4 o;
    o.x = f2bf((v.x - mu) * rs * gg.x + bb.x);
    o.y = f2bf((v.y - mu) * rs * gg.y + bb.y);
    o.z = f2bf((v.z - mu) * rs * gg.z + bb.z);
    o.w = f2bf((v.w - mu) * rs * gg.w + bb.w);
    ((ushort4*)(re_bf + (long)row * 1024))[tid] = o;
  } else {
    for (int i = tid; i < 2048; i += 256)
      idxt[i] = (u16)bucket_idx(i - 1024);
    if (tid < 256){
      int sb = tid >> 4, tt = tid & 15;
      int dlo = sb * 64 - tt * 64 - 63;
      int lo = bucket_idx(dlo) & ~1;
      if (lo > 384) lo = 384;
      ixlo_tbl[tid] = (u16)lo;
    }
    for (int i = tid; i < 1024; i += 256){
      qkvb[i] = bq[i]; qkvb[1024 + i] = bk[i]; qkvb[2048 + i] = bv[i];
      posb[i] = bpk[i]; posb[1024 + i] = bpq[i];
    }
  }
}

// ---------------- MFMA GEMM (unchanged from R5) ----------------
template<int MODE>
__global__ __launch_bounds__(256) void k_gemm(
    const u16* __restrict__ A, const u16* __restrict__ Bt,
    const float* __restrict__ bias, void* __restrict__ C, void* __restrict__ C2,
    int M, int N, int K, int lda, int ldb)
{
  __shared__ __attribute__((aligned(16))) u16 smem[16384];
  u16* As = smem;
  u16* Bs = smem + 8192;
  const int z = blockIdx.z;
  const u16* Ab = A;
  const u16* Bb = Bt;
  if (MODE == 3){ Bb = Bt + (long)z * 1048576; bias += z << 10; }
  if (MODE == 4){ Ab = A + (long)z * 65536; Bb = Bt + (long)(z >> 6) * 524288 + (long)(z & 15) * 32768; }
  const int m0 = blockIdx.y * 128, n0 = blockIdx.x * 128;
  const int tid = threadIdx.x, lane = tid & 63, w = tid >> 6;
  const int wm = (w >> 1) * 64, wn = (w & 1) * 64;
  floatx4 acc[4][4];
  #pragma unroll
  for (int i = 0; i < 4; i++)
    #pragma unroll
    for (int j = 0; j < 4; j++) acc[i][j] = (floatx4){0.f, 0.f, 0.f, 0.f};

  const int r8 = lane >> 3;
  const int cswz = ((lane & 7) ^ r8) << 4;

  for (int kt = 0; kt < K; kt += 64){
    #pragma unroll
    for (int c = 0; c < 4; c++){
      int row = (c * 4 + w) * 8 + r8;
      const char* ga = (const char*)(Ab + (long)(m0 + row) * lda + kt) + cswz;
      __builtin_amdgcn_global_load_lds((gas_ptr)ga, (las_ptr)((char*)As + (c * 4 + w) * 1024), 16, 0, 0);
      const char* gb = (const char*)(Bb + (long)(n0 + row) * ldb + kt) + cswz;
      __builtin_amdgcn_global_load_lds((gas_ptr)gb, (las_ptr)((char*)Bs + (c * 4 + w) * 1024), 16, 0, 0);
    }
    __syncthreads();
    short8_t af[2][4], bfr[2][4];
    #pragma unroll
    for (int kk = 0; kk < 2; kk++){
      #pragma unroll
      for (int i = 0; i < 4; i++){
        int ra = wm + i * 16 + (lane & 15);
        af[kk][i] = *(const short8_t*)((const char*)As + ra * 128 + ((kk * 64 + ((lane >> 4) << 4)) ^ ((ra & 7) << 4)));
        int rb = wn + i * 16 + (lane & 15);
        bfr[kk][i] = *(const short8_t*)((const char*)Bs + rb * 128 + ((kk * 64 + ((lane >> 4) << 4)) ^ ((rb & 7) << 4)));
      }
    }
    #pragma unroll
    for (int i = 0; i < 4; i++)
      #pragma unroll
      for (int j = 0; j < 4; j++){
        acc[i][j] = __builtin_amdgcn_mfma_f32_16x16x32_bf16(af[0][i], bfr[0][j], acc[i][j], 0, 0, 0);
        acc[i][j] = __builtin_amdgcn_mfma_f32_16x16x32_bf16(af[1][i], bfr[1][j], acc[i][j], 0, 0, 0);
      }
    __syncthreads();
  }

  if (MODE == 5 && n0 >= 2048){
    #pragma unroll
    for (int i = 0; i < 4; i++){
      #pragma unroll
      for (int j = 0; j < 4; j++){
        #pragma unroll
        for (int r = 0; r < 4; r++){
          int ml = wm + i * 16 + ((lane >> 4) << 2) + r;
          int nl = wn + j * 16 + (lane & 15);
          float v = acc[i][j][r] + bias[n0 + nl];
          int byte_ = nl * 256 + ((ml * 2) ^ ((nl & 7) << 4));
          *(u16*)((char*)smem + byte_) = f2bf(v);
        }
      }
    }
    __syncthreads();
    #pragma unroll
    for (int rr = 0; rr < 8; rr++){
      int nl = rr * 16 + (tid >> 4);
      int np = n0 + nl - 2048;
      int mc = tid & 15;
      short8_t vv = *(const short8_t*)((const char*)smem + nl * 256 + ((mc * 16) ^ ((nl & 7) << 4)));
      int m = m0 + mc * 8;
      long base = ((long)((m >> 10) * 16 + (np >> 6)) * 64 + (np & 63)) * 1024 + (m & 1023);
      *(short8_t*)((u16*)C2 + base) = vv;
    }
    return;
  }

  #pragma unroll
  for (int i = 0; i < 4; i++){
    #pragma unroll
    for (int j = 0; j < 4; j++){
      #pragma unroll
      for (int r = 0; r < 4; r++){
        int m = m0 + wm + i * 16 + ((lane >> 4) << 2) + r;
        int n = n0 + wn + j * 16 + (lane & 15);
        float v = acc[i][j][r] + (bias ? bias[n] : 0.f);
        if (MODE == 0){
          ((float*)C)[(long)m * N + n] = v;
        } else if (MODE == 3){
          ((u16*)C)[(long)z * 524288 + ((long)(n >> 6) * 512 + m) * 64 + (n & 63)] = f2bf(v);
        } else if (MODE == 4){
          ((u16*)C)[(long)z * 524288 + (long)m * 512 + n] = f2bf(v);
        } else if (MODE == 5){
          int mat = n >> 10;
          int np = n & 1023;
          ((u16*)C)[(long)mat * 4194304 +
                    ((long)((m >> 10) * 16 + (np >> 6)) * 1024 + (m & 1023)) * 64 + (np & 63)] = f2bf(v);
        }
      }
    }
  }
}

// ---------------- k_bias: EB[bh][s][k] = exp2((c2p+p2c)*sB2) ----------------
// grid 1024 (xcd-chunked -> (bh, sb)), 256 thr = 4 waves; loops 16 k-tiles.
// Uses R5's proven window staging (STAGEROW XOR-preswizzle) + IDW + ixlo.
__global__ __launch_bounds__(256, 4) void k_bias(
    const u16* __restrict__ c2p, const u16* __restrict__ p2c,
    const u16* __restrict__ T3, const u16* __restrict__ ixlo_tbl,
    u16* __restrict__ EB)
{
  __shared__ __attribute__((aligned(16))) u16 C2W[8192];   // [64 s][128]
  __shared__ __attribute__((aligned(16))) u16 P2W[8192];   // [64 k][128]
  __shared__ __attribute__((aligned(16))) u16 IDW[128];
  const int flat0 = blockIdx.x;
  const int flat = (flat0 & 7) * 128 + (flat0 >> 3);
  const int bh = flat >> 4, sb = flat & 15;
  const int tid = threadIdx.x, lane = tid & 63, w = tid >> 6;
  const int s0 = sb * 64;
  const u16* c2b = c2p + (long)bh * 524288;
  const u16* p2b = p2c + (long)bh * 524288;
  u16* EBb = EB + ((long)bh << 20);
  const float sB2 = 0.12751743f;   // log2(e)/sqrt(128)

  const int r2 = tid >> 2;         // s_local 0..63
  const int q2 = tid & 3;          // k quarter
  const int c2key = (r2 & 15) << 4;

  auto STAGEROW = [&](const u16* rowptr, u16* ldsbase, int row){
    const char* src = (const char*)rowptr + (((lane * 4) ^ ((row & 15) << 4)));
    __builtin_amdgcn_global_load_lds((gas_ptr)src, (las_ptr)((char*)ldsbase + row * 256), 4, 0, 0);
  };

  for (int t = 0; t < 16; t++){
    const int k0 = t * 64;
    const int ixlo = (int)ixlo_tbl[sb * 16 + t];
    #pragma unroll
    for (int r = 0; r < 16; r++){
      int row = w * 16 + r;
      STAGEROW(c2b + (long)(s0 + row) * 512 + ixlo, C2W, row);
      STAGEROW(p2b + (long)(k0 + row) * 512 + ixlo, P2W, row);
    }
    if (w == 0){
      int dev = s0 - k0 - 64;
      __builtin_amdgcn_global_load_lds((gas_ptr)((const char*)(T3 + (dev + 1024)) + lane * 4),
                                       (las_ptr)((char*)IDW), 4, 0, 0);
    }
    __syncthreads();

    u16 ov[16];
    #pragma unroll
    for (int c = 0; c < 16; c++){
      int kl = q2 * 16 + c;
      int j = r2 - kl + 64;
      int ix = (int)IDW[j];
      int x = (ix - ixlo) * 2;
      u16 b1 = *(const u16*)((const char*)C2W + r2 * 256 + (x ^ c2key));
      u16 b2 = *(const u16*)((const char*)P2W + kl * 256 + (x ^ ((kl & 15) << 4)));
      ov[c] = f2bf(exp2f((bf2f(b1) + bf2f(b2)) * sB2));
    }
    u16* dst = EBb + (((long)(s0 + r2)) << 10) + k0 + q2 * 16;
    uint4 st0, st1;
    st0.x = (unsigned)ov[0]  | ((unsigned)ov[1]  << 16);
    st0.y = (unsigned)ov[2]  | ((unsigned)ov[3]  << 16);
    st0.z = (unsigned)ov[4]  | ((unsigned)ov[5]  << 16);
    st0.w = (unsigned)ov[6]  | ((unsigned)ov[7]  << 16);
    st1.x = (unsigned)ov[8]  | ((unsigned)ov[9]  << 16);
    st1.y = (unsigned)ov[10] | ((unsigned)ov[11] << 16);
    st1.z = (unsigned)ov[12] | ((unsigned)ov[13] << 16);
    st1.w = (unsigned)ov[14] | ((unsigned)ov[15] << 16);
    *(uint4*)dst = st0;
    *(uint4*)(dst + 8) = st1;
    __syncthreads();
  }
}

// ---------------- k_attn_eb: streaming flash attn, bias pre-exp'd ----------------
// grid 1024 (xcd-chunked), 256 thr = 4 waves. One raw barrier/tile, counted vmcnt.
// LDS 48KB -> 3 blocks/CU. EB rows wave-private (no barrier for EB).
__global__ __launch_bounds__(256, 3) void k_attn_eb(
    const u16* __restrict__ Q, const u16* __restrict__ K, const u16* __restrict__ Vt,
    const u16* __restrict__ EB, u16* __restrict__ ctx)
{
  __shared__ __attribute__((aligned(16))) u16 Ks[2][4096];
  __shared__ __attribute__((aligned(16))) u16 Vs[2][4096];
  __shared__ __attribute__((aligned(16))) u16 EBs[4096];
  __shared__ __attribute__((aligned(16))) u16 Pt[4096];
  const int flat0 = blockIdx.x;
  const int flat = (flat0 & 7) * 128 + (flat0 >> 3);
  const int bh = flat >> 4, sb = flat & 15;
  const int tid = threadIdx.x, lane = tid & 63, w = tid >> 6;
  const int s15 = lane & 15, g = lane >> 4;
  const int s0 = sb * 64;
  const int myrow = w * 16 + s15;
  const int s_row = s0 + myrow;
  const u16* Qb  = Q   + (long)bh * 65536;
  const u16* Kg  = K   + (long)bh * 65536;
  const u16* Vg  = Vt  + (long)bh * 65536;
  const u16* EBg = EB  + ((long)bh << 20);

  // qf loads first (oldest in vmcnt queue; compiler guards their use)
  short8_t qf0 = *(const short8_t*)(Qb + (long)s_row * 64 + g * 8);
  short8_t qf1 = *(const short8_t*)(Qb + (long)s_row * 64 + 32 + g * 8);

  const int srow8  = lane >> 3;
  const int schunk = (lane & 7) ^ srow8;
  const float sA2 = 0.10411754f;   // log2(e)/sqrt(192)

  auto STAGE_KV = [&](int buf, int kt){
    #pragma unroll
    for (int ii = 0; ii < 2; ii++){
      int i = w * 2 + ii;
      int row = i * 8 + srow8;
      __builtin_amdgcn_global_load_lds(
        (gas_ptr)((const char*)(Kg + (long)(kt + row) * 64) + schunk * 16),
        (las_ptr)((char*)&Ks[buf][0] + i * 1024), 16, 0, 0);
      __builtin_amdgcn_global_load_lds(
        (gas_ptr)((const char*)(Vg + (long)row * 1024 + kt) + schunk * 16),
        (las_ptr)((char*)&Vs[buf][0] + i * 1024), 16, 0, 0);
    }
  };
  auto STAGE_EB = [&](int kt){
    #pragma unroll
    for (int ii = 0; ii < 2; ii++){
      int rowl = w * 16 + ii * 8 + srow8;
      const char* src = (const char*)(EBg + (((long)(s0 + rowl)) << 10) + kt) + schunk * 16;
      __builtin_amdgcn_global_load_lds((gas_ptr)src,
        (las_ptr)((char*)EBs + (w * 2 + ii) * 1024), 16, 0, 0);
    }
  };

  STAGE_KV(0, 0);   // 4 loads
  STAGE_EB(0);      // 2 loads

  float rowsum = 0.f;
  floatx4 oacc[4];
  #pragma unroll
  for (int dt = 0; dt < 4; dt++) oacc[dt] = (floatx4){0.f, 0.f, 0.f, 0.f};

  const int psw = (myrow & 7) << 4;

  for (int t = 0; t < 16; t++){
    const int buf = t & 1;
    const int kt = t * 64;

    // wait: everything except EB(t) [2 youngest] done -> KV(t) landed
    asm volatile("s_waitcnt vmcnt(2)" ::: "memory");
    __builtin_amdgcn_s_barrier();   // all waves: KV(t) in LDS, done reading buf^1

    STAGE_KV(buf ^ 1, (t < 15) ? kt + 64 : 0);   // 4 loads (youngest from here on)

    // QK^T swapped: a[T] lane holds col s=s15, rows k=T*16+g*4+e
    floatx4 a[4];
    #pragma unroll
    for (int T = 0; T < 4; T++){
      int row = T * 16 + s15;
      const char* rp = (const char*)&Ks[buf][0] + row * 128;
      int sw = (row & 7) << 4;
      short8_t k0v = *(const short8_t*)(rp + ((g * 16) ^ sw));
      short8_t k1v = *(const short8_t*)(rp + ((64 + g * 16) ^ sw));
      floatx4 acc = (floatx4){0.f, 0.f, 0.f, 0.f};
      acc = __builtin_amdgcn_mfma_f32_16x16x32_bf16(k0v, qf0, acc, 0, 0, 0);
      acc = __builtin_amdgcn_mfma_f32_16x16x32_bf16(k1v, qf1, acc, 0, 0, 0);
      a[T] = acc;
    }

    // wait: everything except KV(t+1) [4 youngest] done -> EB(t) landed
    asm volatile("s_waitcnt vmcnt(4)" ::: "memory");

    #pragma unroll
    for (int T = 0; T < 4; T++){
      uint2 ebv = *(const uint2*)((const char*)EBs + myrow * 128 + ((T * 32 + g * 8) ^ psw));
      float e0 = exp2f(a[T][0] * sA2) * bf2f((u16)(ebv.x & 0xffff));
      float e1 = exp2f(a[T][1] * sA2) * bf2f((u16)(ebv.x >> 16));
      float e2 = exp2f(a[T][2] * sA2) * bf2f((u16)(ebv.y & 0xffff));
      float e3 = exp2f(a[T][3] * sA2) * bf2f((u16)(ebv.y >> 16));
      u16 p0 = f2bf(e0), p1 = f2bf(e1), p2v = f2bf(e2), p3 = f2bf(e3);
      rowsum += (bf2f(p0) + bf2f(p1)) + (bf2f(p2v) + bf2f(p3));
      uint2 pk2;
      pk2.x = (unsigned)p0  | ((unsigned)p1 << 16);
      pk2.y = (unsigned)p2v | ((unsigned)p3 << 16);
      *(uint2*)((char*)Pt + myrow * 128 + ((T * 32 + g * 8) ^ psw)) = pk2;
    }

    // own EB rows consumed; restage for t+1 (wave-private, no barrier)
    asm volatile("s_waitcnt lgkmcnt(0)" ::: "memory");
    STAGE_EB((t < 15) ? kt + 64 : 0);   // 2 loads (new youngest)

    // PV: O[s,d] += P[s,:] V[:,d]
    #pragma unroll
    for (int M = 0; M < 2; M++){
      short8_t pf = *(const short8_t*)((const char*)Pt + myrow * 128 + ((M * 64 + g * 16) ^ psw));
      #pragma unroll
      for (int dt = 0; dt < 4; dt++){
        int drow = dt * 16 + s15;
        short8_t vf = *(const short8_t*)((const char*)&Vs[buf][0] + drow * 128 + ((M * 64 + g * 16) ^ ((drow & 7) << 4)));
        oacc[dt] = __builtin_amdgcn_mfma_f32_16x16x32_bf16(pf, vf, oacc[dt], 0, 0, 0);
      }
    }
  }

  asm volatile("s_waitcnt vmcnt(0)" ::: "memory");   // drain dummy stages before endpgm

  rowsum += __shfl_xor(rowsum, 16);
  rowsum += __shfl_xor(rowsum, 32);
  float rinv = 1.f / rowsum;

  const int b = bh >> 4, h = bh & 15;
  #pragma unroll
  for (int r = 0; r < 4; r++){
    float ri = __shfl(rinv, g * 4 + r);
    int s_out = s0 + w * 16 + g * 4 + r;
    #pragma unroll
    for (int dt = 0; dt < 4; dt++){
      long oi = ((long)b * 1024 + s_out) * 1024 + h * 64 + dt * 16 + s15;
      ctx[oi] = f2bf(oacc[dt][r] * ri);
    }
  }
}

// ---------------- fallback: R5 window-staged attention (proven) ----------------
__global__ __launch_bounds__(256, 2) void k_attn_win(
    const u16* __restrict__ Q, const u16* __restrict__ K, const u16* __restrict__ Vt,
    const u16* __restrict__ c2p, const u16* __restrict__ p2c,
    const u16* __restrict__ T3, const u16* __restrict__ ixlo_tbl,
    u16* __restrict__ ctx)
{
  __shared__ __attribute__((aligned(16))) u16 Ks[2][4096];
  __shared__ __attribute__((aligned(16))) u16 Vs[2][4096];
  __shared__ __attribute__((aligned(16))) u16 Pt[4096];
  __shared__ __attribute__((aligned(16))) u16 C2W[8192];
  __shared__ __attribute__((aligned(16))) u16 P2W[8192];
  __shared__ __attribute__((aligned(16))) u16 IDW[4][128];
  const int flat0 = blockIdx.x;
  const int flat = (flat0 & 7) * 128 + (flat0 >> 3);
  const int bh = flat >> 4, sb = flat & 15;
  const int tid = threadIdx.x, lane = tid & 63, w = tid >> 6;
  const int s15 = lane & 15, g = lane >> 4;
  const int s0 = sb * 64;
  const int myrow = w * 16 + s15;
  const int s_row = s0 + myrow;
  const u16* Qb  = Q   + (long)bh * 65536;
  const u16* Kg  = K   + (long)bh * 65536;
  const u16* Vg  = Vt  + (long)bh * 65536;
  const u16* c2b = c2p + (long)bh * 524288;
  const u16* p2b = p2c + (long)bh * 524288;

  short8_t qf0 = *(const short8_t*)(Qb + (long)s_row * 64 + g * 8);
  short8_t qf1 = *(const short8_t*)(Qb + (long)s_row * 64 + 32 + g * 8);

  const int srow8  = lane >> 3;
  const int schunk = (lane & 7) ^ srow8;
  const float sA2 = 0.10411754f;
  const float sB2 = 0.12751743f;

  auto STAGEKV = [&](int buf, int kt){
    #pragma unroll
    for (int ii = 0; ii < 2; ii++){
      int i = w * 2 + ii;
      int row = i * 8 + srow8;
      __builtin_amdgcn_global_load_lds(
        (gas_ptr)((const char*)(Kg + (long)(kt + row) * 64) + schunk * 16),
        (las_ptr)((char*)&Ks[buf][0] + i * 1024), 16, 0, 0);
      __builtin_amdgcn_global_load_lds(
        (gas_ptr)((const char*)(Vg + (long)row * 1024 + kt) + schunk * 16),
        (las_ptr)((char*)&Vs[buf][0] + i * 1024), 16, 0, 0);
    }
  };
  auto STAGEROW = [&](const u16* rowptr, u16* ldsbase, int row){
    const char* src = (const char*)rowptr + (((lane * 4) ^ ((row & 15) << 4)));
    __builtin_amdgcn_global_load_lds((gas_ptr)src, (las_ptr)((char*)ldsbase + row * 256), 4, 0, 0);
  };

  const int tb16 = sb * 16;
  int ixlo_cur = (int)ixlo_tbl[tb16];

  #pragma unroll
  for (int r = 0; r < 16; r++){
    int row = w * 16 + r;
    STAGEROW(p2b + (long)row * 512 + ixlo_cur, P2W, row);
  }
  {
    int dev = s0 - 64;
    __builtin_amdgcn_global_load_lds((gas_ptr)((const char*)(T3 + (dev + 1024)) + lane * 4),
                                     (las_ptr)((char*)IDW + w * 256), 4, 0, 0);
  }
  STAGEKV(0, 0);

  float rowsum = 0.f;
  floatx4 oacc[4];
  #pragma unroll
  for (int dt = 0; dt < 4; dt++) oacc[dt] = (floatx4){0.f, 0.f, 0.f, 0.f};

  const int psw = (myrow & 7) << 4;
  const int c2wkey = (myrow & 15) << 4;

  __syncthreads();

  for (int t = 0; t < 16; t++){
    const int buf = t & 1;
    const int k0 = t * 64;

    int ixlo_next = 0;
    if (t < 15) ixlo_next = (int)ixlo_tbl[tb16 + t + 1];
    if (t < 15) STAGEKV(buf ^ 1, k0 + 64);
    #pragma unroll
    for (int r = 0; r < 16; r++){
      int row = w * 16 + r;
      STAGEROW(c2b + (long)(s0 + row) * 512 + ixlo_cur, C2W, row);
    }

    floatx4 a[4];
    #pragma unroll
    for (int T = 0; T < 4; T++){
      int row = T * 16 + s15;
      const char* rp = (const char*)&Ks[buf][0] + row * 128;
      int sw = (row & 7) << 4;
      short8_t k0v = *(const short8_t*)(rp + ((g * 16) ^ sw));
      short8_t k1v = *(const short8_t*)(rp + ((64 + g * 16) ^ sw));
      floatx4 acc = (floatx4){0.f, 0.f, 0.f, 0.f};
      acc = __builtin_amdgcn_mfma_f32_16x16x32_bf16(k0v, qf0, acc, 0, 0, 0);
      acc = __builtin_amdgcn_mfma_f32_16x16x32_bf16(k1v, qf1, acc, 0, 0, 0);
      a[T] = acc;
    }

    asm volatile("s_waitcnt vmcnt(0)" ::: "memory");

    #pragma unroll
    for (int T = 0; T < 4; T++){
      int klb = T * 16 + g * 4;
      int jb = myrow + 64 - klb;
      u16 pv[4];
      #pragma unroll
      for (int e = 0; e < 4; e++){
        int ix = (int)*(const u16*)((const char*)IDW + w * 256 + (jb - e) * 2);
        int x = (ix - ixlo_cur) * 2;
        int kl = klb + e;
        u16 b1 = *(const u16*)((const char*)C2W + myrow * 256 + (x ^ c2wkey));
        u16 b2 = *(const u16*)((const char*)P2W + kl * 256 + (x ^ ((kl & 15) << 4)));
        float bs = bf2f(b1) + bf2f(b2);
        float ev = exp2f(a[T][e] * sA2 + bs * sB2);
        pv[e] = f2bf(ev);
        rowsum += bf2f(pv[e]);
      }
      uint2 pk2;
      pk2.x = (unsigned)pv[0] | ((unsigned)pv[1] << 16);
      pk2.y = (unsigned)pv[2] | ((unsigned)pv[3] << 16);
      *(uint2*)((char*)Pt + myrow * 128 + ((T * 32 + g * 8) ^ psw)) = pk2;
    }

    __syncthreads();

    if (t < 15){
      #pragma unroll
      for (int r = 0; r < 16; r++){
        int row = w * 16 + r;
        STAGEROW(p2b + (long)(k0 + 64 + row) * 512 + ixlo_next, P2W, row);
      }
      int dev = s0 - (k0 + 64) - 64;
      __builtin_amdgcn_global_load_lds((gas_ptr)((const char*)(T3 + (dev + 1024)) + lane * 4),
                                       (las_ptr)((char*)IDW + w * 256), 4, 0, 0);
    }

    #pragma unroll
    for (int M = 0; M < 2; M++){
      short8_t pf = *(const short8_t*)((const char*)Pt + myrow * 128 + ((M * 64 + g * 16) ^ psw));
      #pragma unroll
      for (int dt = 0; dt < 4; dt++){
        int drow = dt * 16 + s15;
        short8_t vf = *(const short8_t*)((const char*)&Vs[buf][0] + drow * 128 + ((M * 64 + g * 16) ^ ((drow & 7) << 4)));
        oacc[dt] = __builtin_amdgcn_mfma_f32_16x16x32_bf16(pf, vf, oacc[dt], 0, 0, 0);
      }
    }

    ixlo_cur = ixlo_next;
    __syncthreads();
  }

  rowsum += __shfl_xor(rowsum, 16);
  rowsum += __shfl_xor(rowsum, 32);
  float rinv = 1.f / rowsum;

  const int b = bh >> 4, h = bh & 15;
  #pragma unroll
  for (int r = 0; r < 4; r++){
    float ri = __shfl(rinv, g * 4 + r);
    int s_out = s0 + w * 16 + g * 4 + r;
    #pragma unroll
    for (int dt = 0; dt < 4; dt++){
      long oi = ((long)b * 1024 + s_out) * 1024 + h * 64 + dt * 16 + s15;
      ctx[oi] = f2bf(oacc[dt][r] * ri);
    }
  }
}

// ---------------- launch ----------------
extern "C" void kernel_launch(void* const* d_in, const int* in_sizes, int n_in,
                              void* d_out, int out_size, void* d_ws, size_t ws_size,
                              hipStream_t stream){
  const float* hs  = (const float*)d_in[0];
  const float* Wq  = (const float*)d_in[1];
  const float* bq  = (const float*)d_in[2];
  const float* Wk  = (const float*)d_in[3];
  const float* bk  = (const float*)d_in[4];
  const float* Wv  = (const float*)d_in[5];
  const float* bv  = (const float*)d_in[6];
  const float* Wo  = (const float*)d_in[7];
  const float* bo  = (const float*)d_in[8];
  const float* rel = (const float*)d_in[9];
  const float* lng = (const float*)d_in[10];
  const float* lnb = (const float*)d_in[11];
  const float* Wpk = (const float*)d_in[12];
  const float* bpk = (const float*)d_in[13];
  const float* Wpq = (const float*)d_in[14];
  const float* bpq = (const float*)d_in[15];

  char* ws = (char*)d_ws;
  size_t off = 0;
  auto alloc = [&](size_t bytes){ size_t o = off; off += (bytes + 255) & ~(size_t)255; return o; };
  u16* h_bf   = (u16*)(ws + alloc(4194304UL * 2));
  u16* Wt_all = (u16*)(ws + alloc(6291456UL * 2));
  u16* re_bf  = (u16*)(ws + alloc(524288UL * 2));
  u16* Qd     = (u16*)(ws + alloc(4194304UL * 2));
  u16* Kd     = (u16*)(ws + alloc(4194304UL * 2));
  u16* Vtd    = (u16*)(ws + alloc(4194304UL * 2));
  u16* posk   = (u16*)(ws + alloc(524288UL * 2));
  u16* posq   = (u16*)(ws + alloc(524288UL * 2));
  u16* c2p    = (u16*)(ws + alloc(33554432UL * 2));
  u16* p2c    = (u16*)(ws + alloc(33554432UL * 2));
  u16* ctx    = (u16*)(ws + alloc(4194304UL * 2));
  u16* idxt   = (u16*)(ws + alloc(2048UL * 2));
  u16* ixlo   = (u16*)(ws + alloc(256UL * 2));
  float* qkvb = (float*)(ws + alloc(3072UL * 4));
  float* posb = (float*)(ws + alloc(2048UL * 4));
  u16* EBws   = (u16*)(ws + alloc(67108864UL * 2));   // 128MB, allocated LAST
  const bool use_eb = (ws_size >= off);
  (void)posq; (void)p2c; (void)Kd;

  k_prep<<<6145, 256, 0, stream>>>(hs, Wq, Wk, Wv, Wo, Wpk, Wpq, rel, lng, lnb,
                                   bq, bk, bv, bpk, bpq,
                                   h_bf, Wt_all, re_bf, idxt, ixlo, qkvb, posb);

  k_gemm<5><<<dim3(24, 32, 1), 256, 0, stream>>>(h_bf, Wt_all, qkvb, Qd, Vtd,
                                                 4096, 3072, 1024, 1024, 1024);
  k_gemm<3><<<dim3(8, 4, 2), 256, 0, stream>>>(re_bf, Wt_all + 4194304, posb, posk, nullptr,
                                               512, 1024, 1024, 1024, 1024);
  k_gemm<4><<<dim3(4, 8, 128), 256, 0, stream>>>(Qd, posk, nullptr, c2p, nullptr,
                                                 1024, 512, 64, 64, 64);

  if (use_eb){
    k_bias<<<dim3(1024), 256, 0, stream>>>(c2p, p2c, idxt, ixlo, EBws);
    k_attn_eb<<<dim3(1024), 256, 0, stream>>>(Qd, Kd, Vtd, EBws, ctx);
  } else {
    k_attn_win<<<dim3(1024), 256, 0, stream>>>(Qd, Kd, Vtd, c2p, p2c, idxt, ixlo, ctx);
  }

  k_gemm<0><<<dim3(8, 32, 1), 256, 0, stream>>>(ctx, Wt_all + 3145728, bo, d_out, nullptr,
                                                4096, 1024, 1024, 1024, 1024);
}